// Round 2
// baseline (665.729 us; speedup 1.0000x reference)
//
#include <hip/hip_runtime.h>
#include <hip/hip_bf16.h>

typedef unsigned short u16;
typedef u16   u16x8 __attribute__((ext_vector_type(8)));
typedef short s16x8 __attribute__((ext_vector_type(8)));
typedef float f32x4 __attribute__((ext_vector_type(4)));

__device__ __forceinline__ float bf2f(u16 u) {
    union { unsigned int i; float f; } v; v.i = ((unsigned int)u) << 16; return v.f;
}
__device__ __forceinline__ u16 f2bf(float f) {
    unsigned int x = __float_as_uint(f);
    return (u16)((x + 0x7fffu + ((x >> 16) & 1u)) >> 16);   // RNE
}
// dual-dtype scalar load: flag=1 -> f32 buffer, flag=0 -> bf16 buffer
__device__ __forceinline__ float ldv(const void* p, size_t i, int f32) {
    return f32 ? ((const float*)p)[i] : bf2f(((const u16*)p)[i]);
}

// ---------------------------------------------------------------------------
// dtype autodetect: low u16 of each u32 word of N(0,1) data is a plausible
// bf16 value iff the buffer is packed bf16. Writes flag: 1 = f32, 0 = bf16.
// ---------------------------------------------------------------------------
__global__ void detect_dtype(const unsigned int* __restrict__ probe, int* __restrict__ flag)
{
    __shared__ int cnt;
    if (threadIdx.x == 0) cnt = 0;
    __syncthreads();
    unsigned int w = probe[threadIdx.x];
    float a = fabsf(bf2f((u16)(w & 0xFFFFu)));
    if (a > 1e-6f && a < 1e4f) atomicAdd(&cnt, 1);
    __syncthreads();
    if (threadIdx.x == 0) *flag = (cnt >= 128) ? 0 : 1;
}

// ---------------------------------------------------------------------------
// canonicalize the 21 weight/bias tensors to bf16 in CAN (952384 elems)
// ---------------------------------------------------------------------------
struct P21 { const void* p[21]; };

__global__ void canon_k(P21 a, const int* __restrict__ flag, u16* __restrict__ CAN)
{
    const int offs[22] = {0,294912,295168,590080,590208,737664,737792,770560,770688,
                          770944,787328,787456,795648,795712,861248,861376,877760,
                          877888,886080,886144,952256,952384};
    int g = blockIdx.x * 256 + threadIdx.x;
    if (g >= 952384) return;
    int f32 = *flag;
    int seg = 0;
    #pragma unroll
    for (int i = 1; i < 22; ++i) seg += (g >= offs[i]);
    int idx = g - offs[seg];
    CAN[g] = f32 ? f2bf(((const float*)a.p[seg])[idx]) : ((const u16*)a.p[seg])[idx];
}

// ---------------------------------------------------------------------------
// Unified GEMM: C = A[M][K] * Bt[nt][K]^T (+bias per-m, optional lrelu).
// 64x64 tile / block, 4 waves, mfma_f32_16x16x32_bf16.
// Output col index = nbase + local n.  CTR=0: C[m][nbase+n], row stride ldc.
// CTR=1: C^T[nbase+n][m] (bf16) via LDS bounce, row stride M.
// ---------------------------------------------------------------------------
template<int ACT, int CTR, int OUT_BF16>
__global__ __launch_bounds__(256) void gemm_kn(
    const u16* __restrict__ A, const u16* __restrict__ Bt,
    const u16* __restrict__ bias, void* __restrict__ Cv,
    int M, int K, int ldc, int nbase)
{
    __shared__ __align__(16) u16 smem[5120];          // 2 x [64][40] bf16 tiles
    u16 (*As)[40] = (u16(*)[40])smem;
    u16 (*Bs)[40] = (u16(*)[40])(smem + 2560);

    const int t    = threadIdx.x;
    const int wv   = t >> 6, lane = t & 63;
    const int fr   = lane & 15, fg = lane >> 4;
    const int tiles_m = M >> 6;
    const int bm = blockIdx.x % tiles_m, bn = blockIdx.x / tiles_m;
    const int m0 = bm << 6, n0 = bn << 6;

    f32x4 acc[4] = {};

    const int srow = t >> 2;            // 0..63
    const int scol = (t & 3) << 3;      // 0,8,16,24
    const u16* Ap = A  + (size_t)(m0 + srow) * K + scol;
    const u16* Bp = Bt + (size_t)(n0 + srow) * K + scol;

    for (int k0 = 0; k0 < K; k0 += 32) {
        uint4 av = *(const uint4*)(Ap + k0);
        uint4 bv = *(const uint4*)(Bp + k0);
        __syncthreads();                               // prev-iter LDS reads done
        *(uint4*)&As[srow][scol] = av;
        *(uint4*)&Bs[srow][scol] = bv;
        __syncthreads();
        union U { uint4 q; s16x8 v; };
        U af; af.q = *(const uint4*)&As[(wv << 4) + fr][fg << 3];
        U bf[4];
        #pragma unroll
        for (int j = 0; j < 4; ++j)
            bf[j].q = *(const uint4*)&Bs[(j << 4) + fr][fg << 3];
        #pragma unroll
        for (int j = 0; j < 4; ++j)
            acc[j] = __builtin_amdgcn_mfma_f32_16x16x32_bf16(af.v, bf[j].v, acc[j], 0, 0, 0);
    }

    // epilogue: bias + activation  (C/D: row=(lane>>4)*4+r, col=lane&15)
    float vv[4][4];
    #pragma unroll
    for (int r = 0; r < 4; ++r) {
        float bvv = bf2f(bias[m0 + (wv << 4) + (fg << 2) + r]);
        #pragma unroll
        for (int j = 0; j < 4; ++j) {
            float v = acc[j][r] + bvv;
            if (ACT) v = (v >= 0.f) ? v : 0.1f * v;
            vv[j][r] = v;
        }
    }

    if (!CTR) {
        #pragma unroll
        for (int j = 0; j < 4; ++j)
            #pragma unroll
            for (int r = 0; r < 4; ++r) {
                size_t idx = (size_t)(m0 + (wv << 4) + (fg << 2) + r) * ldc
                           + (nbase + n0 + (j << 4) + fr);
                if (OUT_BF16) ((u16*)Cv)[idx] = f2bf(vv[j][r]);
                else          ((float*)Cv)[idx] = vv[j][r];
            }
    } else {
        __syncthreads();
        u16* bb = smem;                                 // [64 n][72 m]
        #pragma unroll
        for (int j = 0; j < 4; ++j)
            #pragma unroll
            for (int r = 0; r < 4; ++r)
                bb[((j << 4) + fr) * 72 + (wv << 4) + (fg << 2) + r] = f2bf(vv[j][r]);
        __syncthreads();
        int row = t >> 2, seg = (t & 3) << 4;
        const uint4* src = (const uint4*)&bb[row * 72 + seg];
        uint4* dst = (uint4*)((u16*)Cv + (size_t)(nbase + n0 + row) * M + m0 + seg);
        dst[0] = src[0];
        dst[1] = src[1];
    }
}

// ---------------------------------------------------------------------------
// cat/value input chunk (one batch image b): CATT[n][256], n in [0,7680)
// ---------------------------------------------------------------------------
__global__ void cat_build(const void* __restrict__ f00, const void* __restrict__ f01,
                          const void* __restrict__ f10, const void* __restrict__ f11,
                          const u16* __restrict__ lvl_emb, u16* __restrict__ CATT,
                          const int* __restrict__ flag, int b)
{
    int g = blockIdx.x * 256 + threadIdx.x;          // 7680*32
    if (g >= 7680 * 32) return;
    int f32 = *flag;
    int n = g >> 5, c0 = (g & 31) << 3;
    int lvl = (n >= 6144) ? 1 : 0;
    int ns = lvl ? n - 6144 : n;
    int HW = lvl ? 1536 : 6144;
    u16x8 v;
    #pragma unroll
    for (int j = 0; j < 8; ++j) {
        int c = c0 + j, cc = c & 127;
        const void* f = (c < 128) ? (lvl ? f01 : f00) : (lvl ? f11 : f10);
        float x = ldv(f, (size_t)(b * 128 + cc) * HW + ns, f32);
        v[j] = f2bf(x + bf2f(lvl_emb[lvl * 128 + cc]));
    }
    *(u16x8*)(CATT + (size_t)n * 256 + c0) = v;
}

// ---------------------------------------------------------------------------
// im2col (3x3 pad1), one batch image: input variant (dual dtype, NCHW d_in)
// ---------------------------------------------------------------------------
__global__ void im2col_in(const void* __restrict__ src, u16* __restrict__ col,
                          const int* __restrict__ flag, int b)
{
    int g = blockIdx.x * 256 + threadIdx.x;          // 1536*144 (K=1152)
    if (g >= 1536 * 144) return;
    int f32 = *flag;
    int hw = g / 144, c0 = (g % 144) << 3;
    int hp = hw / 48, wp = hw % 48;
    u16x8 v;
    #pragma unroll
    for (int j = 0; j < 8; ++j) {
        int k = c0 + j, ci = k / 9, rr = k - ci * 9, ky = rr / 3, kx = rr - ky * 3;
        int hh = hp + ky - 1, ww = wp + kx - 1;
        float x = 0.f;
        if (hh >= 0 && hh < 32 && ww >= 0 && ww < 48)
            x = ldv(src, (size_t)(b * 128 + ci) * 1536 + hh * 48 + ww, f32);
        v[j] = f2bf(x);
    }
    *(u16x8*)(col + (size_t)hw * 1152 + c0) = v;
}

// ws variant: src is bf16 [CIN][6144] (channel-major across full batch)
__global__ void im2col_ws(const u16* __restrict__ src, u16* __restrict__ col,
                          int CIN, int b)
{
    int K = CIN * 9, cpr = K >> 3;
    int g = blockIdx.x * 256 + threadIdx.x;
    if (g >= 1536 * cpr) return;
    int hw = g / cpr, c0 = (g % cpr) << 3;
    int hp = hw / 48, wp = hw % 48;
    u16x8 v;
    #pragma unroll
    for (int j = 0; j < 8; ++j) {
        int k = c0 + j, ci = k / 9, rr = k - ci * 9, ky = rr / 3, kx = rr - ky * 3;
        int hh = hp + ky - 1, ww = wp + kx - 1;
        u16 x = 0;
        if (hh >= 0 && hh < 32 && ww >= 0 && ww < 48)
            x = src[(size_t)ci * 6144 + b * 1536 + hh * 48 + ww];
        v[j] = x;
    }
    *(u16x8*)(col + (size_t)hw * K + c0) = v;
}

// ---------------------------------------------------------------------------
// sine pos-enc added in place to QT0[tok][128]
// ---------------------------------------------------------------------------
__global__ void pos_add(u16* __restrict__ QT)
{
    int g = blockIdx.x * 256 + threadIdx.x;          // 6144*16
    if (g >= 6144 * 16) return;
    int tok = g >> 4, d0 = (g & 15) << 3;
    int hw = tok % 1536;
    int hp = hw / 48, wp = hw % 48;
    const float TWO_PI = 6.283185307179586f;
    float yv = (float)(hp + 1) * (TWO_PI / (32.f + 1e-6f));
    float xv = (float)(wp + 1) * (TWO_PI / (48.f + 1e-6f));
    u16x8 v = *(u16x8*)(QT + (size_t)tok * 128 + d0);
    #pragma unroll
    for (int j = 0; j < 8; ++j) {
        int dd = d0 + j;
        int m = (dd & 63) >> 1;
        float dim = exp2f((float)m * (13.287712379549449f / 32.f));   // 10000^(m/32)
        float val = ((dd < 64) ? yv : xv) / dim;
        float pos = (dd & 1) ? cosf(val) : sinf(val);
        v[j] = f2bf(bf2f(v[j]) + pos);
    }
    *(u16x8*)(QT + (size_t)tok * 128 + d0) = v;
}

// ---------------------------------------------------------------------------
// weight prep (from canonical bf16): APJ = [so_w^T ; aw_w^T], AOP = op_w^T,
// BPJ = [so_b ; aw_b]
// ---------------------------------------------------------------------------
__global__ void prep_weights(
    const u16* sw0, const u16* awm0, const u16* sb0, const u16* ab0, const u16* ow0,
    const u16* sw1, const u16* awm1, const u16* sb1, const u16* ab1, const u16* ow1,
    u16* APJ0, u16* APJ1, u16* AOP0, u16* AOP1, u16* BPJ0, u16* BPJ1)
{
    int g = blockIdx.x * 256 + threadIdx.x;
    if (g < 24576) { int o = g >> 7, d = g & 127;
        APJ0[g] = (o < 128) ? sw0[d * 128 + o] : awm0[d * 64 + (o - 128)]; return; }
    g -= 24576;
    if (g < 24576) { int o = g >> 7, d = g & 127;
        APJ1[g] = (o < 128) ? sw1[d * 128 + o] : awm1[d * 64 + (o - 128)]; return; }
    g -= 24576;
    if (g < 65536) { int o = g >> 9, k = g & 511; AOP0[g] = ow0[k * 128 + o]; return; }
    g -= 65536;
    if (g < 65536) { int o = g >> 9, k = g & 511; AOP1[g] = ow1[k * 128 + o]; return; }
    g -= 65536;
    if (g < 192) { BPJ0[g] = (g < 128) ? sb0[g] : ab0[g - 128]; return; }
    g -= 192;
    if (g < 192) { BPJ1[g] = (g < 128) ? sb1[g] : ab1[g - 128]; return; }
}

// ---------------------------------------------------------------------------
// MSDeformAttn sampling (+softmax fused)
// PA: [192][6144] f32 (rows 0..127 offsets, 128..191 logits)
// VAL: [30720][128] bf16, S out: [6144][512] bf16
// ---------------------------------------------------------------------------
__global__ void msda_sample(const float* __restrict__ PA, const u16* __restrict__ VAL,
                            u16* __restrict__ S)
{
    __shared__ int   SMI[4][64];
    __shared__ float SMW[4][64];
    __shared__ float LG[64];
    __shared__ float EW[64];
    int tok = blockIdx.x;                 // 0..6143
    int t = threadIdx.x;                  // 128
    int b = tok / 1536, hw = tok % 1536;
    int hp = hw / 48, wp = hw % 48;

    if (t < 64) {
        int l = (t >> 3) & 1, p = t & 7, h = t >> 4;
        int orow = h * 32 + l * 16 + p * 2;
        float offx = PA[(size_t)orow * 6144 + tok];
        float offy = PA[(size_t)(orow + 1) * 6144 + tok];
        LG[t]      = PA[(size_t)(128 + h * 16 + l * 8 + p) * 6144 + tok];
        float Wl = l ? 48.f : 96.f, Hl = l ? 32.f : 64.f;
        int iWl = l ? 48 : 96, iHl = l ? 32 : 64;
        int base = l ? 6144 : 0;
        float locx = (wp + 0.5f) / 48.f + offx / Wl;
        float locy = (hp + 0.5f) / 32.f + offy / Hl;
        float x = locx * Wl - 0.5f;
        float y = locy * Hl - 0.5f;
        float xf = floorf(x), yf = floorf(y);
        float fx = x - xf, fy = y - yf;
        int ix = (int)xf, iy = (int)yf;
        int vrow = b * 7680 + base;
        float w00 = (1.f - fx) * (1.f - fy), w01 = fx * (1.f - fy);
        float w10 = (1.f - fx) * fy,         w11 = fx * fy;
        bool vx0 = (ix >= 0) & (ix < iWl),     vx1 = (ix + 1 >= 0) & (ix + 1 < iWl);
        bool vy0 = (iy >= 0) & (iy < iHl),     vy1 = (iy + 1 >= 0) & (iy + 1 < iHl);
        SMI[0][t] = (vx0 & vy0) ? vrow + iy * iWl + ix           : -1;  SMW[0][t] = w00;
        SMI[1][t] = (vx1 & vy0) ? vrow + iy * iWl + ix + 1       : -1;  SMW[1][t] = w01;
        SMI[2][t] = (vx0 & vy1) ? vrow + (iy + 1) * iWl + ix     : -1;  SMW[2][t] = w10;
        SMI[3][t] = (vx1 & vy1) ? vrow + (iy + 1) * iWl + ix + 1 : -1;  SMW[3][t] = w11;
    }
    __syncthreads();
    if (t < 64) {
        int h0 = t & ~15;
        float mx = -1e30f;
        for (int i = 0; i < 16; ++i) mx = fmaxf(mx, LG[h0 + i]);
        EW[t] = expf(LG[t] - mx);
    }
    __syncthreads();
    if (t < 64) {
        int h0 = t & ~15;
        float s = 0.f;
        for (int i = 0; i < 16; ++i) s += EW[h0 + i];
        float aw = EW[t] / s;
        SMW[0][t] *= aw; SMW[1][t] *= aw; SMW[2][t] *= aw; SMW[3][t] *= aw;
    }
    __syncthreads();

    int d = t;                                   // 0..127
    for (int h = 0; h < 4; ++h) {
        float acc = 0.f;
        for (int s16i = 0; s16i < 16; ++s16i) {
            int sm = (h << 4) + s16i;
            #pragma unroll
            for (int c = 0; c < 4; ++c) {
                int idx = SMI[c][sm];
                float w = SMW[c][sm];
                if (idx >= 0) acc += w * bf2f(VAL[(size_t)idx * 128 + d]);
            }
        }
        S[(size_t)tok * 512 + (h << 7) + d] = f2bf(acc);
    }
}

// ---------------------------------------------------------------------------
// final: out[b][d][hw] = QT[b*1536+hw][d]  (dual-dtype store)
// ---------------------------------------------------------------------------
__global__ void write_out(const u16* __restrict__ QT, void* __restrict__ out,
                          const int* __restrict__ flag)
{
    int g = blockIdx.x * 256 + threadIdx.x;      // 98304
    if (g >= 98304) return;
    int f32 = *flag;
    int hw0 = (g % 192) << 3;
    int r = g / 192;                             // b*128 + d
    int d = r & 127, b = r >> 7;
    float vv[8];
    #pragma unroll
    for (int j = 0; j < 8; ++j)
        vv[j] = bf2f(QT[(size_t)(b * 1536 + hw0 + j) * 128 + d]);
    if (f32) {
        float4 x0 = { vv[0], vv[1], vv[2], vv[3] };
        float4 x1 = { vv[4], vv[5], vv[6], vv[7] };
        float4* dst = (float4*)((float*)out + (size_t)r * 1536 + hw0);
        dst[0] = x0; dst[1] = x1;
    } else {
        u16x8 v;
        #pragma unroll
        for (int j = 0; j < 8; ++j) v[j] = f2bf(vv[j]);
        *(u16x8*)((u16*)out + (size_t)r * 1536 + hw0) = v;
    }
}

// ---------------------------------------------------------------------------
extern "C" void kernel_launch(void* const* d_in, const int* in_sizes, int n_in,
                              void* d_out, int out_size, void* d_ws, size_t ws_size,
                              hipStream_t stream)
{
    (void)in_sizes; (void)n_in; (void)out_size; (void)ws_size;

    char* ws = (char*)d_ws;
    size_t off = 0;
    auto alloc = [&](size_t bytes) { size_t o = off; off += (bytes + 255) & ~(size_t)255; return o; };
    int*   FLAG = (int*)(ws + alloc(256));
    u16*   CAN  = (u16*)(ws + alloc(952384ull * 2));
    u16*   VAL  = (u16*)(ws + alloc(30720ull * 128 * 2));
    u16*   COLc = (u16*)(ws + alloc(1536ull * 2304 * 2));   // also CATT chunk [7680][256]
    u16*   CH1  = (u16*)(ws + alloc(256ull * 6144 * 2));
    u16*   CH2  = (u16*)(ws + alloc(128ull * 6144 * 2));
    u16*   QT0  = (u16*)(ws + alloc(6144ull * 128 * 2));    // also final QT2
    u16*   QT1  = (u16*)(ws + alloc(6144ull * 128 * 2));
    float* PA   = (float*)(ws + alloc(192ull * 6144 * 4));
    u16*   S    = (u16*)(ws + alloc(6144ull * 512 * 2));
    u16*   APJ0 = (u16*)(ws + alloc(192ull * 128 * 2));
    u16*   APJ1 = (u16*)(ws + alloc(192ull * 128 * 2));
    u16*   AOP0 = (u16*)(ws + alloc(128ull * 512 * 2));
    u16*   AOP1 = (u16*)(ws + alloc(128ull * 512 * 2));
    u16*   BPJ0 = (u16*)(ws + alloc(512));
    u16*   BPJ1 = (u16*)(ws + alloc(512));

    // canonical weight/bias offsets (elements in CAN)
    u16* cw1C = CAN + 0;      u16* cb1C = CAN + 294912;
    u16* cw2C = CAN + 295168; u16* cb2C = CAN + 590080;
    u16* cw3C = CAN + 590208; u16* cb3C = CAN + 737664;
    u16* vwC  = CAN + 737792; u16* vbC  = CAN + 770560;
    u16* lvlC = CAN + 770688;
    u16* sw0C = CAN + 770944; u16* sb0C = CAN + 787328;
    u16* aw0C = CAN + 787456; u16* ab0C = CAN + 795648;
    u16* ow0C = CAN + 795712; u16* ob0C = CAN + 861248;
    u16* sw1C = CAN + 861376; u16* sb1C = CAN + 877760;
    u16* aw1C = CAN + 877888; u16* ab1C = CAN + 886080;
    u16* ow1C = CAN + 886144; u16* ob1C = CAN + 952256;

    // 0. dtype detect + canonicalize weights
    detect_dtype<<<1, 256, 0, stream>>>((const unsigned int*)d_in[0], FLAG);
    P21 a;
    const int widx[21] = {4,5,6,7,8,9,10,11,12, 13,14,15,16,17,18, 19,20,21,22,23,24};
    for (int i = 0; i < 21; ++i) a.p[i] = d_in[widx[i]];
    canon_k<<<3721, 256, 0, stream>>>(a, FLAG, CAN);
    prep_weights<<<706, 256, 0, stream>>>(sw0C, aw0C, sb0C, ab0C, ow0C,
                                          sw1C, aw1C, sb1C, ab1C, ow1C,
                                          APJ0, APJ1, AOP0, AOP1, BPJ0, BPJ1);

    // 1. value path (chunked per batch image)
    for (int b = 0; b < 4; ++b) {
        cat_build<<<960, 256, 0, stream>>>(d_in[0], d_in[1], d_in[2], d_in[3],
                                           lvlC, COLc, FLAG, b);
        gemm_kn<0, 1, 1><<<2 * 120, 256, 0, stream>>>(vwC, COLc, vbC, VAL,
                                                      128, 256, 0, b * 7680);
    }
    // 2. conv stack (chunked im2col + GEMM)
    for (int b = 0; b < 4; ++b) {
        im2col_in<<<864, 256, 0, stream>>>(d_in[1], COLc, FLAG, b);
        gemm_kn<1, 0, 1><<<4 * 24, 256, 0, stream>>>(cw1C, COLc, cb1C, CH1,
                                                     256, 1152, 6144, b * 1536);
    }
    for (int b = 0; b < 4; ++b) {
        im2col_ws<<<1728, 256, 0, stream>>>(CH1, COLc, 256, b);
        gemm_kn<1, 0, 1><<<2 * 24, 256, 0, stream>>>(cw2C, COLc, cb2C, CH2,
                                                     128, 2304, 6144, b * 1536);
    }
    for (int b = 0; b < 4; ++b) {
        im2col_ws<<<864, 256, 0, stream>>>(CH2, COLc, 128, b);
        gemm_kn<1, 1, 1><<<2 * 24, 256, 0, stream>>>(cw3C, COLc, cb3C, QT0,
                                                     128, 1152, 0, b * 1536);
    }
    pos_add<<<384, 256, 0, stream>>>(QT0);

    // 3. attention block 0
    gemm_kn<0, 0, 0><<<3 * 96, 256, 0, stream>>>(APJ0, QT0, BPJ0, PA, 192, 128, 6144, 0);
    msda_sample<<<6144, 128, 0, stream>>>(PA, VAL, S);
    gemm_kn<0, 1, 1><<<2 * 96, 256, 0, stream>>>(AOP0, S, ob0C, QT1, 128, 512, 0, 0);

    // 4. attention block 1
    gemm_kn<0, 0, 0><<<3 * 96, 256, 0, stream>>>(APJ1, QT1, BPJ1, PA, 192, 128, 6144, 0);
    msda_sample<<<6144, 128, 0, stream>>>(PA, VAL, S);
    gemm_kn<0, 1, 1><<<2 * 96, 256, 0, stream>>>(AOP1, S, ob1C, QT0, 128, 512, 0, 0);

    // 5. final layout
    write_out<<<384, 256, 0, stream>>>(QT0, d_out, FLAG);
}

// Round 3
// 208.966 us; speedup vs baseline: 3.1858x; 3.1858x over previous
//
#include <hip/hip_runtime.h>
#include <hip/hip_bf16.h>

typedef unsigned short u16;
typedef u16   u16x8 __attribute__((ext_vector_type(8)));
typedef short s16x8 __attribute__((ext_vector_type(8)));
typedef float f32x4 __attribute__((ext_vector_type(4)));

__device__ __forceinline__ float bf2f(u16 u) {
    union { unsigned int i; float f; } v; v.i = ((unsigned int)u) << 16; return v.f;
}
__device__ __forceinline__ u16 f2bf(float f) {
    unsigned int x = __float_as_uint(f);
    return (u16)((x + 0x7fffu + ((x >> 16) & 1u)) >> 16);   // RNE
}
__device__ __forceinline__ float ldv(const void* p, size_t i, int f32) {
    return f32 ? ((const float*)p)[i] : bf2f(((const u16*)p)[i]);
}

// ---------------------------------------------------------------------------
// dtype autodetect (bf16 vs f32 device buffers)
// ---------------------------------------------------------------------------
__global__ void detect_dtype(const unsigned int* __restrict__ probe, int* __restrict__ flag)
{
    __shared__ int cnt;
    if (threadIdx.x == 0) cnt = 0;
    __syncthreads();
    unsigned int w = probe[threadIdx.x];
    float a = fabsf(bf2f((u16)(w & 0xFFFFu)));
    if (a > 1e-6f && a < 1e4f) atomicAdd(&cnt, 1);
    __syncthreads();
    if (threadIdx.x == 0) *flag = (cnt >= 128) ? 0 : 1;
}

// ---------------------------------------------------------------------------
// canonicalize the 21 weight/bias tensors to bf16 in CAN (952384 elems)
// ---------------------------------------------------------------------------
struct P21 { const void* p[21]; };

__global__ void canon_k(P21 a, const int* __restrict__ flag, u16* __restrict__ CAN)
{
    const int offs[22] = {0,294912,295168,590080,590208,737664,737792,770560,770688,
                          770944,787328,787456,795648,795712,861248,861376,877760,
                          877888,886080,886144,952256,952384};
    int g = blockIdx.x * 256 + threadIdx.x;
    if (g >= 952384) return;
    int f32 = *flag;
    int seg = 0;
    #pragma unroll
    for (int i = 1; i < 22; ++i) seg += (g >= offs[i]);
    int idx = g - offs[seg];
    CAN[g] = f32 ? f2bf(((const float*)a.p[seg])[idx]) : ((const u16*)a.p[seg])[idx];
}

// ---------------------------------------------------------------------------
// weight prep: APJ=[so_w^T;aw_w^T], AOP=op_w^T, BPJ=[so_b;aw_b],
// AWc[m][tap*CIN+ci] = cw[m][ci][tap]  (tap-major reorder for implicit conv)
// ---------------------------------------------------------------------------
__global__ void prep_weights(
    const u16* sw0, const u16* awm0, const u16* sb0, const u16* ab0, const u16* ow0,
    const u16* sw1, const u16* awm1, const u16* sb1, const u16* ab1, const u16* ow1,
    const u16* cw1, const u16* cw2, const u16* cw3,
    u16* APJ0, u16* APJ1, u16* AOP0, u16* AOP1, u16* BPJ0, u16* BPJ1,
    u16* AW1, u16* AW2, u16* AW3)
{
    int g = blockIdx.x * 256 + threadIdx.x;
    if (g < 24576) { int o = g >> 7, d = g & 127;
        APJ0[g] = (o < 128) ? sw0[d * 128 + o] : awm0[d * 64 + (o - 128)]; return; }
    g -= 24576;
    if (g < 24576) { int o = g >> 7, d = g & 127;
        APJ1[g] = (o < 128) ? sw1[d * 128 + o] : awm1[d * 64 + (o - 128)]; return; }
    g -= 24576;
    if (g < 65536) { int o = g >> 9, k = g & 511; AOP0[g] = ow0[k * 128 + o]; return; }
    g -= 65536;
    if (g < 65536) { int o = g >> 9, k = g & 511; AOP1[g] = ow1[k * 128 + o]; return; }
    g -= 65536;
    if (g < 192) { BPJ0[g] = (g < 128) ? sb0[g] : ab0[g - 128]; return; }
    g -= 192;
    if (g < 192) { BPJ1[g] = (g < 128) ? sb1[g] : ab1[g - 128]; return; }
    g -= 192;
    if (g < 294912) {  // AW1: M=256, CIN=128
        int m = g / 1152, rem = g % 1152, tap = rem >> 7, ci = rem & 127;
        AW1[g] = cw1[(size_t)m * 1152 + ci * 9 + tap]; return; }
    g -= 294912;
    if (g < 294912) {  // AW2: M=128, CIN=256
        int m = g / 2304, rem = g % 2304, tap = rem >> 8, ci = rem & 255;
        AW2[g] = cw2[(size_t)m * 2304 + ci * 9 + tap]; return; }
    g -= 294912;
    if (g < 147456) {  // AW3: M=128, CIN=128
        int m = g / 1152, rem = g % 1152, tap = rem >> 7, ci = rem & 127;
        AW3[g] = cw3[(size_t)m * 1152 + ci * 9 + tap]; return; }
}

// ---------------------------------------------------------------------------
// Unified GEMM: C = A[M][K] * Bt[N][K]^T (+bias per-m, optional lrelu)
// 64x64 tile, 4 waves, mfma_f32_16x16x32_bf16. CTR=1: write C^T via LDS bounce.
// ---------------------------------------------------------------------------
template<int ACT, int CTR, int OUT_BF16>
__global__ __launch_bounds__(256) void gemm_kn(
    const u16* __restrict__ A, const u16* __restrict__ Bt,
    const u16* __restrict__ bias, void* __restrict__ Cv,
    int M, int K, int ldc, int nbase)
{
    __shared__ __align__(16) u16 smem[5120];          // 2 x [64][40] bf16 tiles
    u16 (*As)[40] = (u16(*)[40])smem;
    u16 (*Bs)[40] = (u16(*)[40])(smem + 2560);

    const int t    = threadIdx.x;
    const int wv   = t >> 6, lane = t & 63;
    const int fr   = lane & 15, fg = lane >> 4;
    const int tiles_m = M >> 6;
    const int bm = blockIdx.x % tiles_m, bn = blockIdx.x / tiles_m;
    const int m0 = bm << 6, n0 = bn << 6;

    f32x4 acc[4] = {};
    const int srow = t >> 2;
    const int scol = (t & 3) << 3;
    const u16* Ap = A  + (size_t)(m0 + srow) * K + scol;
    const u16* Bp = Bt + (size_t)(n0 + srow) * K + scol;

    for (int k0 = 0; k0 < K; k0 += 32) {
        uint4 av = *(const uint4*)(Ap + k0);
        uint4 bv = *(const uint4*)(Bp + k0);
        __syncthreads();
        *(uint4*)&As[srow][scol] = av;
        *(uint4*)&Bs[srow][scol] = bv;
        __syncthreads();
        union U { uint4 q; s16x8 v; };
        U af; af.q = *(const uint4*)&As[(wv << 4) + fr][fg << 3];
        U bf[4];
        #pragma unroll
        for (int j = 0; j < 4; ++j)
            bf[j].q = *(const uint4*)&Bs[(j << 4) + fr][fg << 3];
        #pragma unroll
        for (int j = 0; j < 4; ++j)
            acc[j] = __builtin_amdgcn_mfma_f32_16x16x32_bf16(af.v, bf[j].v, acc[j], 0, 0, 0);
    }

    float vv[4][4];
    #pragma unroll
    for (int r = 0; r < 4; ++r) {
        float bvv = bf2f(bias[m0 + (wv << 4) + (fg << 2) + r]);
        #pragma unroll
        for (int j = 0; j < 4; ++j) {
            float v = acc[j][r] + bvv;
            if (ACT) v = (v >= 0.f) ? v : 0.1f * v;
            vv[j][r] = v;
        }
    }

    if (!CTR) {
        #pragma unroll
        for (int j = 0; j < 4; ++j)
            #pragma unroll
            for (int r = 0; r < 4; ++r) {
                size_t idx = (size_t)(m0 + (wv << 4) + (fg << 2) + r) * ldc
                           + (nbase + n0 + (j << 4) + fr);
                if (OUT_BF16) ((u16*)Cv)[idx] = f2bf(vv[j][r]);
                else          ((float*)Cv)[idx] = vv[j][r];
            }
    } else {
        __syncthreads();
        u16* bb = smem;                                 // [64 n][72 m]
        #pragma unroll
        for (int j = 0; j < 4; ++j)
            #pragma unroll
            for (int r = 0; r < 4; ++r)
                bb[((j << 4) + fr) * 72 + (wv << 4) + (fg << 2) + r] = f2bf(vv[j][r]);
        __syncthreads();
        int row = t >> 2, seg = (t & 3) << 4;
        const uint4* src = (const uint4*)&bb[row * 72 + seg];
        uint4* dst = (uint4*)((u16*)Cv + (size_t)(nbase + n0 + row) * M + m0 + seg);
        dst[0] = src[0];
        dst[1] = src[1];
    }
}

// ---------------------------------------------------------------------------
// Implicit-GEMM 3x3 conv (pad 1): C^T[tok][M] = lrelu(AW * X^T + bias)
// AW[m][tap*CIN+ci], X[6144][CIN] token-major. Tap loop shifts B row offset;
// invalid rows masked to zero. Tiles never cross image boundary (1536%64==0).
// ---------------------------------------------------------------------------
template<int CIN>
__global__ __launch_bounds__(256) void conv_gemm(
    const u16* __restrict__ A, const u16* __restrict__ X,
    const u16* __restrict__ bias, u16* __restrict__ Cv, int M)
{
    __shared__ __align__(16) u16 smem[5120];
    u16 (*As)[40] = (u16(*)[40])smem;
    u16 (*Bs)[40] = (u16(*)[40])(smem + 2560);

    const int t    = threadIdx.x;
    const int wv   = t >> 6, lane = t & 63;
    const int fr   = lane & 15, fg = lane >> 4;
    const int tiles_m = M >> 6;
    const int bm = blockIdx.x % tiles_m, bn = blockIdx.x / tiles_m;
    const int m0 = bm << 6, n0 = bn << 6;

    const int srow = t >> 2;
    const int scol = (t & 3) << 3;
    const int n  = n0 + srow;
    const int hw = n % 1536;
    const int hp = hw / 48, wp = hw % 48;
    const u16* Ar = A + (size_t)(m0 + srow) * (9 * CIN) + scol;

    f32x4 acc[4] = {};

    #pragma unroll
    for (int tap = 0; tap < 9; ++tap) {
        const int dy = tap / 3 - 1, dx = tap % 3 - 1;
        const bool vr = ((unsigned)(hp + dy) < 32u) && ((unsigned)(wp + dx) < 48u);
        const u16* Bp = X + (vr ? (size_t)(n + dy * 48 + dx) * CIN : 0) + scol;
        const u16* Ap = Ar + tap * CIN;
        for (int k0 = 0; k0 < CIN; k0 += 32) {
            uint4 av = *(const uint4*)(Ap + k0);
            uint4 bv = *(const uint4*)(Bp + k0);
            if (!vr) bv = uint4{0, 0, 0, 0};
            __syncthreads();
            *(uint4*)&As[srow][scol] = av;
            *(uint4*)&Bs[srow][scol] = bv;
            __syncthreads();
            union U { uint4 q; s16x8 v; };
            U af; af.q = *(const uint4*)&As[(wv << 4) + fr][fg << 3];
            U bf[4];
            #pragma unroll
            for (int j = 0; j < 4; ++j)
                bf[j].q = *(const uint4*)&Bs[(j << 4) + fr][fg << 3];
            #pragma unroll
            for (int j = 0; j < 4; ++j)
                acc[j] = __builtin_amdgcn_mfma_f32_16x16x32_bf16(af.v, bf[j].v, acc[j], 0, 0, 0);
        }
    }

    float vv[4][4];
    #pragma unroll
    for (int r = 0; r < 4; ++r) {
        float bvv = bf2f(bias[m0 + (wv << 4) + (fg << 2) + r]);
        #pragma unroll
        for (int j = 0; j < 4; ++j) {
            float v = acc[j][r] + bvv;
            vv[j][r] = (v >= 0.f) ? v : 0.1f * v;
        }
    }

    __syncthreads();
    u16* bb = smem;
    #pragma unroll
    for (int j = 0; j < 4; ++j)
        #pragma unroll
        for (int r = 0; r < 4; ++r)
            bb[((j << 4) + fr) * 72 + (wv << 4) + (fg << 2) + r] = f2bf(vv[j][r]);
    __syncthreads();
    int row = t >> 2, seg = (t & 3) << 4;
    const uint4* src = (const uint4*)&bb[row * 72 + seg];
    uint4* dst = (uint4*)(Cv + (size_t)(n0 + row) * M + m0 + seg);
    dst[0] = src[0];
    dst[1] = src[1];
}

// ---------------------------------------------------------------------------
// conv1 input: X0[b*1536+hw][ci] = feat0_l1[b][ci][hw]  (dual dtype)
// ---------------------------------------------------------------------------
__global__ void xpose_in(const void* __restrict__ src, u16* __restrict__ X0,
                         const int* __restrict__ flag)
{
    int g = blockIdx.x * 256 + threadIdx.x;          // 6144*16
    if (g >= 6144 * 16) return;
    int f32 = *flag;
    int c = g & 127;
    int tok0 = (g >> 7) << 3;
    int b = tok0 / 1536, hw = tok0 % 1536;
    #pragma unroll
    for (int j = 0; j < 8; ++j) {
        float x = ldv(src, (size_t)(b * 128 + c) * 1536 + hw + j, f32);
        X0[(size_t)(tok0 + j) * 128 + c] = f2bf(x);
    }
}

// ---------------------------------------------------------------------------
// cat/value input full batch: CATT[b*7680+n][256]
// ---------------------------------------------------------------------------
__global__ void cat_build(const void* __restrict__ f00, const void* __restrict__ f01,
                          const void* __restrict__ f10, const void* __restrict__ f11,
                          const u16* __restrict__ lvl_emb, u16* __restrict__ CATT,
                          const int* __restrict__ flag)
{
    int g = blockIdx.x * 256 + threadIdx.x;          // 30720*32
    if (g >= 30720 * 32) return;
    int f32 = *flag;
    int tok = g >> 5, c0 = (g & 31) << 3;
    int b = tok / 7680, n = tok % 7680;
    int lvl = (n >= 6144) ? 1 : 0;
    int ns = lvl ? n - 6144 : n;
    int HW = lvl ? 1536 : 6144;
    u16x8 v;
    #pragma unroll
    for (int j = 0; j < 8; ++j) {
        int c = c0 + j, cc = c & 127;
        const void* f = (c < 128) ? (lvl ? f01 : f00) : (lvl ? f11 : f10);
        float x = ldv(f, (size_t)(b * 128 + cc) * HW + ns, f32);
        v[j] = f2bf(x + bf2f(lvl_emb[lvl * 128 + cc]));
    }
    *(u16x8*)(CATT + (size_t)tok * 256 + c0) = v;
}

// ---------------------------------------------------------------------------
// sine pos-enc added in place to QT0[tok][128]
// ---------------------------------------------------------------------------
__global__ void pos_add(u16* __restrict__ QT)
{
    int g = blockIdx.x * 256 + threadIdx.x;          // 6144*16
    if (g >= 6144 * 16) return;
    int tok = g >> 4, d0 = (g & 15) << 3;
    int hw = tok % 1536;
    int hp = hw / 48, wp = hw % 48;
    const float TWO_PI = 6.283185307179586f;
    float yv = (float)(hp + 1) * (TWO_PI / (32.f + 1e-6f));
    float xv = (float)(wp + 1) * (TWO_PI / (48.f + 1e-6f));
    u16x8 v = *(u16x8*)(QT + (size_t)tok * 128 + d0);
    #pragma unroll
    for (int j = 0; j < 8; ++j) {
        int dd = d0 + j;
        int m = (dd & 63) >> 1;
        float dim = exp2f((float)m * (13.287712379549449f / 32.f));   // 10000^(m/32)
        float val = ((dd < 64) ? yv : xv) / dim;
        float pos = (dd & 1) ? cosf(val) : sinf(val);
        v[j] = f2bf(bf2f(v[j]) + pos);
    }
    *(u16x8*)(QT + (size_t)tok * 128 + d0) = v;
}

// ---------------------------------------------------------------------------
// MSDeformAttn sampling (+softmax), vectorized gather.
// Phase2: thread t -> head h=t>>5, dseg=(t&15), half=(t>>4)&1. Each thread
// accumulates 32 of 64 weighted rows over its 16B dim-segment; halves
// combined via shfl_xor(16). Invalid corners: weight 0, index clamped to 0.
// ---------------------------------------------------------------------------
__global__ void msda_sample(const float* __restrict__ PA, const u16* __restrict__ VAL,
                            u16* __restrict__ S)
{
    __shared__ int   SMI[4][64];
    __shared__ float SMW[4][64];
    __shared__ float LG[64];
    __shared__ float EW[64];
    int tok = blockIdx.x;
    int t = threadIdx.x;                  // 128
    int b = tok / 1536, hw = tok % 1536;
    int hp = hw / 48, wp = hw % 48;

    if (t < 64) {
        int l = (t >> 3) & 1, p = t & 7, h = t >> 4;
        int orow = h * 32 + l * 16 + p * 2;
        float offx = PA[(size_t)orow * 6144 + tok];
        float offy = PA[(size_t)(orow + 1) * 6144 + tok];
        LG[t]      = PA[(size_t)(128 + h * 16 + l * 8 + p) * 6144 + tok];
        float Wl = l ? 48.f : 96.f, Hl = l ? 32.f : 64.f;
        int iWl = l ? 48 : 96, iHl = l ? 32 : 64;
        int base = l ? 6144 : 0;
        float locx = (wp + 0.5f) / 48.f + offx / Wl;
        float locy = (hp + 0.5f) / 32.f + offy / Hl;
        float x = locx * Wl - 0.5f;
        float y = locy * Hl - 0.5f;
        float xf = floorf(x), yf = floorf(y);
        float fx = x - xf, fy = y - yf;
        int ix = (int)xf, iy = (int)yf;
        int vrow = b * 7680 + base;
        float w00 = (1.f - fx) * (1.f - fy), w01 = fx * (1.f - fy);
        float w10 = (1.f - fx) * fy,         w11 = fx * fy;
        bool vx0 = (ix >= 0) & (ix < iWl),     vx1 = (ix + 1 >= 0) & (ix + 1 < iWl);
        bool vy0 = (iy >= 0) & (iy < iHl),     vy1 = (iy + 1 >= 0) & (iy + 1 < iHl);
        SMI[0][t] = (vx0 & vy0) ? vrow + iy * iWl + ix           : 0;
        SMI[1][t] = (vx1 & vy0) ? vrow + iy * iWl + ix + 1       : 0;
        SMI[2][t] = (vx0 & vy1) ? vrow + (iy + 1) * iWl + ix     : 0;
        SMI[3][t] = (vx1 & vy1) ? vrow + (iy + 1) * iWl + ix + 1 : 0;
        SMW[0][t] = (vx0 & vy0) ? w00 : 0.f;
        SMW[1][t] = (vx1 & vy0) ? w01 : 0.f;
        SMW[2][t] = (vx0 & vy1) ? w10 : 0.f;
        SMW[3][t] = (vx1 & vy1) ? w11 : 0.f;
    }
    __syncthreads();
    if (t < 64) {
        int h0 = t & ~15;
        float mx = -1e30f;
        for (int i = 0; i < 16; ++i) mx = fmaxf(mx, LG[h0 + i]);
        EW[t] = expf(LG[t] - mx);
    }
    __syncthreads();
    if (t < 64) {
        int h0 = t & ~15;
        float s = 0.f;
        for (int i = 0; i < 16; ++i) s += EW[h0 + i];
        float aw = EW[t] / s;
        SMW[0][t] *= aw; SMW[1][t] *= aw; SMW[2][t] *= aw; SMW[3][t] *= aw;
    }
    __syncthreads();

    const int h = t >> 5, sub = t & 31, dseg = sub & 15, half = sub >> 4;
    const u16* Vb = VAL + (size_t)dseg * 8;
    float acc[8] = {0.f, 0.f, 0.f, 0.f, 0.f, 0.f, 0.f, 0.f};
    #pragma unroll 8
    for (int r = 0; r < 32; ++r) {
        int pr = (half << 5) + r;
        int s = pr >> 2, c = pr & 3;
        float w  = SMW[c][(h << 4) + s];
        int  idx = SMI[c][(h << 4) + s];
        u16x8 v = *(const u16x8*)(Vb + (size_t)idx * 128);
        #pragma unroll
        for (int j = 0; j < 8; ++j) acc[j] += w * bf2f(v[j]);
    }
    #pragma unroll
    for (int j = 0; j < 8; ++j) acc[j] += __shfl_xor(acc[j], 16, 64);
    if (!half) {
        u16x8 o;
        #pragma unroll
        for (int j = 0; j < 8; ++j) o[j] = f2bf(acc[j]);
        *(u16x8*)(S + (size_t)tok * 512 + (h << 7) + (dseg << 3)) = o;
    }
}

// ---------------------------------------------------------------------------
// final: out[b][d][hw] = QT[b*1536+hw][d]  (dual-dtype store)
// ---------------------------------------------------------------------------
__global__ void write_out(const u16* __restrict__ QT, void* __restrict__ out,
                          const int* __restrict__ flag)
{
    int g = blockIdx.x * 256 + threadIdx.x;      // 98304
    if (g >= 98304) return;
    int f32 = *flag;
    int hw0 = (g % 192) << 3;
    int r = g / 192;                             // b*128 + d
    int d = r & 127, b = r >> 7;
    float vv[8];
    #pragma unroll
    for (int j = 0; j < 8; ++j)
        vv[j] = bf2f(QT[(size_t)(b * 1536 + hw0 + j) * 128 + d]);
    if (f32) {
        float4 x0 = { vv[0], vv[1], vv[2], vv[3] };
        float4 x1 = { vv[4], vv[5], vv[6], vv[7] };
        float4* dst = (float4*)((float*)out + (size_t)r * 1536 + hw0);
        dst[0] = x0; dst[1] = x1;
    } else {
        u16x8 v;
        #pragma unroll
        for (int j = 0; j < 8; ++j) v[j] = f2bf(vv[j]);
        *(u16x8*)((u16*)out + (size_t)r * 1536 + hw0) = v;
    }
}

// ---------------------------------------------------------------------------
extern "C" void kernel_launch(void* const* d_in, const int* in_sizes, int n_in,
                              void* d_out, int out_size, void* d_ws, size_t ws_size,
                              hipStream_t stream)
{
    (void)in_sizes; (void)n_in; (void)out_size; (void)ws_size;

    char* ws = (char*)d_ws;
    size_t off = 0;
    auto alloc = [&](size_t bytes) { size_t o = off; off += (bytes + 255) & ~(size_t)255; return o; };
    int*   FLAG = (int*)(ws + alloc(256));
    u16*   CAN  = (u16*)(ws + alloc(952384ull * 2));
    u16*   AW1  = (u16*)(ws + alloc(294912ull * 2));
    u16*   AW2  = (u16*)(ws + alloc(294912ull * 2));
    u16*   AW3  = (u16*)(ws + alloc(147456ull * 2));
    u16*   APJ0 = (u16*)(ws + alloc(24576ull * 2));
    u16*   APJ1 = (u16*)(ws + alloc(24576ull * 2));
    u16*   AOP0 = (u16*)(ws + alloc(65536ull * 2));
    u16*   AOP1 = (u16*)(ws + alloc(65536ull * 2));
    u16*   BPJ0 = (u16*)(ws + alloc(512));
    u16*   BPJ1 = (u16*)(ws + alloc(512));
    u16*   VAL  = (u16*)(ws + alloc(30720ull * 128 * 2));
    u16*   X0   = (u16*)(ws + alloc(6144ull * 128 * 2));
    u16*   CH1  = (u16*)(ws + alloc(6144ull * 256 * 2));
    u16*   CH2  = (u16*)(ws + alloc(6144ull * 128 * 2));
    u16*   QT0  = (u16*)(ws + alloc(6144ull * 128 * 2));
    u16*   QT1  = (u16*)(ws + alloc(6144ull * 128 * 2));
    char*  R    = ws + alloc(30720ull * 256 * 2);          // union: CATT | PA+S
    u16*   CATT = (u16*)R;
    float* PA   = (float*)R;
    u16*   S    = (u16*)(R + 192ull * 6144 * 4);

    u16* cw1C = CAN + 0;      u16* cb1C = CAN + 294912;
    u16* cw2C = CAN + 295168; u16* cb2C = CAN + 590080;
    u16* cw3C = CAN + 590208; u16* cb3C = CAN + 737664;
    u16* vwC  = CAN + 737792; u16* vbC  = CAN + 770560;
    u16* lvlC = CAN + 770688;
    u16* sw0C = CAN + 770944; u16* sb0C = CAN + 787328;
    u16* aw0C = CAN + 787456; u16* ab0C = CAN + 795648;
    u16* ow0C = CAN + 795712; u16* ob0C = CAN + 861248;
    u16* sw1C = CAN + 861376; u16* sb1C = CAN + 877760;
    u16* aw1C = CAN + 877888; u16* ab1C = CAN + 886080;
    u16* ow1C = CAN + 886144; u16* ob1C = CAN + 952256;

    // 0. dtype detect + canonicalize + weight prep
    detect_dtype<<<1, 256, 0, stream>>>((const unsigned int*)d_in[0], FLAG);
    P21 a;
    const int widx[21] = {4,5,6,7,8,9,10,11,12, 13,14,15,16,17,18, 19,20,21,22,23,24};
    for (int i = 0; i < 21; ++i) a.p[i] = d_in[widx[i]];
    canon_k<<<3721, 256, 0, stream>>>(a, FLAG, CAN);
    prep_weights<<<3586, 256, 0, stream>>>(sw0C, aw0C, sb0C, ab0C, ow0C,
                                           sw1C, aw1C, sb1C, ab1C, ow1C,
                                           cw1C, cw2C, cw3C,
                                           APJ0, APJ1, AOP0, AOP1, BPJ0, BPJ1,
                                           AW1, AW2, AW3);

    // 1. value path (full batch)
    cat_build<<<3840, 256, 0, stream>>>(d_in[0], d_in[1], d_in[2], d_in[3], lvlC, CATT, FLAG);
    gemm_kn<0, 1, 1><<<2 * 480, 256, 0, stream>>>(vwC, CATT, vbC, VAL, 128, 256, 0, 0);

    // 2. conv stack (implicit GEMM, full batch each)
    xpose_in<<<384, 256, 0, stream>>>(d_in[1], X0, FLAG);
    conv_gemm<128><<<4 * 96, 256, 0, stream>>>(AW1, X0,  cb1C, CH1, 256);
    conv_gemm<256><<<2 * 96, 256, 0, stream>>>(AW2, CH1, cb2C, CH2, 128);
    conv_gemm<128><<<2 * 96, 256, 0, stream>>>(AW3, CH2, cb3C, QT0, 128);
    pos_add<<<384, 256, 0, stream>>>(QT0);

    // 3. attention block 0
    gemm_kn<0, 0, 0><<<3 * 96, 256, 0, stream>>>(APJ0, QT0, BPJ0, PA, 192, 128, 6144, 0);
    msda_sample<<<6144, 128, 0, stream>>>(PA, VAL, S);
    gemm_kn<0, 1, 1><<<2 * 96, 256, 0, stream>>>(AOP0, S, ob0C, QT1, 128, 512, 0, 0);

    // 4. attention block 1
    gemm_kn<0, 0, 0><<<3 * 96, 256, 0, stream>>>(APJ1, QT1, BPJ1, PA, 192, 128, 6144, 0);
    msda_sample<<<6144, 128, 0, stream>>>(PA, VAL, S);
    gemm_kn<0, 1, 1><<<2 * 96, 256, 0, stream>>>(AOP1, S, ob1C, QT0, 128, 512, 0, 0);

    // 5. final layout
    write_out<<<384, 256, 0, stream>>>(QT0, d_out, FLAG);
}

// Round 4
// 198.226 us; speedup vs baseline: 3.3584x; 1.0542x over previous
//
#include <hip/hip_runtime.h>
#include <hip/hip_bf16.h>

typedef unsigned short u16;
typedef u16   u16x8 __attribute__((ext_vector_type(8)));
typedef short s16x8 __attribute__((ext_vector_type(8)));
typedef float f32x4 __attribute__((ext_vector_type(4)));

__device__ __forceinline__ float bf2f(u16 u) {
    union { unsigned int i; float f; } v; v.i = ((unsigned int)u) << 16; return v.f;
}
__device__ __forceinline__ u16 f2bf(float f) {
    unsigned int x = __float_as_uint(f);
    return (u16)((x + 0x7fffu + ((x >> 16) & 1u)) >> 16);   // RNE
}
__device__ __forceinline__ float ldv(const void* p, size_t i, int f32) {
    return f32 ? ((const float*)p)[i] : bf2f(((const u16*)p)[i]);
}

// ---------------------------------------------------------------------------
// dtype autodetect (bf16 vs f32 device buffers)
// ---------------------------------------------------------------------------
__global__ void detect_dtype(const unsigned int* __restrict__ probe, int* __restrict__ flag)
{
    __shared__ int cnt;
    if (threadIdx.x == 0) cnt = 0;
    __syncthreads();
    unsigned int w = probe[threadIdx.x];
    float a = fabsf(bf2f((u16)(w & 0xFFFFu)));
    if (a > 1e-6f && a < 1e4f) atomicAdd(&cnt, 1);
    __syncthreads();
    if (threadIdx.x == 0) *flag = (cnt >= 128) ? 0 : 1;
}

// ---------------------------------------------------------------------------
// single prep kernel: reads RAW inputs (dual dtype), emits all bf16 operands:
// AW1/2/3 conv weights tap-major, AVW=vw, APJ=[so_w^T;aw_w^T], AOP=op_w^T,
// BPJ=[so_b;aw_b], SB = cb1|cb2|cb3|vb|lvl|ob0|ob1
// ---------------------------------------------------------------------------
struct P21 { const void* p[21]; };
// p[] order: 0 cw1, 1 cb1, 2 cw2, 3 cb2, 4 cw3, 5 cb3, 6 vw, 7 vb, 8 lvl,
//            9 sw0, 10 sb0, 11 aw0, 12 ab0, 13 ow0, 14 ob0,
//            15 sw1, 16 sb1, 17 aw1, 18 ab1, 19 ow1, 20 ob1

__global__ void prep_all(P21 a, const int* __restrict__ flag,
                         u16* AW1, u16* AW2, u16* AW3, u16* AVW,
                         u16* APJ0, u16* APJ1, u16* AOP0, u16* AOP1,
                         u16* BPJ0, u16* BPJ1, u16* SB)
{
    int g = blockIdx.x * 256 + threadIdx.x;          // 951808 total
    int f32 = *flag;
    if (g < 294912) { int m = g / 1152, rem = g % 1152, tap = rem >> 7, ci = rem & 127;
        AW1[g] = f2bf(ldv(a.p[0], (size_t)m * 1152 + ci * 9 + tap, f32)); return; }
    g -= 294912;
    if (g < 294912) { int m = g / 2304, rem = g % 2304, tap = rem >> 8, ci = rem & 255;
        AW2[g] = f2bf(ldv(a.p[2], (size_t)m * 2304 + ci * 9 + tap, f32)); return; }
    g -= 294912;
    if (g < 147456) { int m = g / 1152, rem = g % 1152, tap = rem >> 7, ci = rem & 127;
        AW3[g] = f2bf(ldv(a.p[4], (size_t)m * 1152 + ci * 9 + tap, f32)); return; }
    g -= 147456;
    if (g < 32768) { AVW[g] = f2bf(ldv(a.p[6], g, f32)); return; }
    g -= 32768;
    if (g < 24576) { int o = g >> 7, d = g & 127;
        APJ0[g] = f2bf(o < 128 ? ldv(a.p[9], d * 128 + o, f32)
                               : ldv(a.p[11], d * 64 + (o - 128), f32)); return; }
    g -= 24576;
    if (g < 24576) { int o = g >> 7, d = g & 127;
        APJ1[g] = f2bf(o < 128 ? ldv(a.p[15], d * 128 + o, f32)
                               : ldv(a.p[17], d * 64 + (o - 128), f32)); return; }
    g -= 24576;
    if (g < 65536) { int o = g >> 9, k = g & 511; AOP0[g] = f2bf(ldv(a.p[13], k * 128 + o, f32)); return; }
    g -= 65536;
    if (g < 65536) { int o = g >> 9, k = g & 511; AOP1[g] = f2bf(ldv(a.p[19], k * 128 + o, f32)); return; }
    g -= 65536;
    if (g < 192) { BPJ0[g] = f2bf(g < 128 ? ldv(a.p[10], g, f32) : ldv(a.p[12], g - 128, f32)); return; }
    g -= 192;
    if (g < 192) { BPJ1[g] = f2bf(g < 128 ? ldv(a.p[16], g, f32) : ldv(a.p[18], g - 128, f32)); return; }
    g -= 192;
    if (g < 1152) {
        const int off[8] = {0, 256, 384, 512, 640, 896, 1024, 1152};
        const int src[7] = {1, 3, 5, 7, 8, 14, 20};
        int s = 0;
        #pragma unroll
        for (int i = 1; i < 7; ++i) s += (g >= off[i]);
        SB[g] = f2bf(ldv(a.p[src[s]], g - off[s], f32)); return;
    }
}

// ---------------------------------------------------------------------------
// Unified GEMM: C = A[M][K] * Bt[N][K]^T (+bias per-m, optional lrelu)
// 64x64 tile, 4 waves, mfma_f32_16x16x32_bf16, prefetch-pipelined K-loop.
// OUTM=0: C[m][nbase+n] row-major (ldc).  OUTM=1: C^T[nbase+n][m] via bounce.
// OUTM=2: NCHW final out[b][m][hw] (dual dtype via flag) via bounce.
// ---------------------------------------------------------------------------
template<int ACT, int OUTM, int OUT_BF16>
__global__ __launch_bounds__(256) void gemm_kn(
    const u16* __restrict__ A, const u16* __restrict__ Bt,
    const u16* __restrict__ bias, void* __restrict__ Cv,
    int M, int K, int ldc, int nbase, const int* __restrict__ flag)
{
    __shared__ __align__(16) u16 smem[5120];          // 2 x [64][40] bf16 tiles
    u16 (*As)[40] = (u16(*)[40])smem;
    u16 (*Bs)[40] = (u16(*)[40])(smem + 2560);

    const int t    = threadIdx.x;
    const int wv   = t >> 6, lane = t & 63;
    const int fr   = lane & 15, fg = lane >> 4;
    const int tiles_m = M >> 6;
    const int bm = blockIdx.x % tiles_m, bn = blockIdx.x / tiles_m;
    const int m0 = bm << 6, n0 = bn << 6;

    f32x4 acc[4] = {};
    const int srow = t >> 2;
    const int scol = (t & 3) << 3;
    const u16* Ap = A  + (size_t)(m0 + srow) * K + scol;
    const u16* Bp = Bt + (size_t)(n0 + srow) * K + scol;

    const int nk = K >> 5;
    uint4 av = *(const uint4*)Ap;
    uint4 bv = *(const uint4*)Bp;
    for (int s = 0; s < nk; ++s) {
        __syncthreads();
        *(uint4*)&As[srow][scol] = av;
        *(uint4*)&Bs[srow][scol] = bv;
        __syncthreads();
        if (s + 1 < nk) {                          // prefetch under MFMA
            av = *(const uint4*)(Ap + ((s + 1) << 5));
            bv = *(const uint4*)(Bp + ((s + 1) << 5));
        }
        union U { uint4 q; s16x8 v; };
        U af; af.q = *(const uint4*)&As[(wv << 4) + fr][fg << 3];
        U bf[4];
        #pragma unroll
        for (int j = 0; j < 4; ++j)
            bf[j].q = *(const uint4*)&Bs[(j << 4) + fr][fg << 3];
        #pragma unroll
        for (int j = 0; j < 4; ++j)
            acc[j] = __builtin_amdgcn_mfma_f32_16x16x32_bf16(af.v, bf[j].v, acc[j], 0, 0, 0);
    }

    float vv[4][4];
    #pragma unroll
    for (int r = 0; r < 4; ++r) {
        float bvv = bf2f(bias[m0 + (wv << 4) + (fg << 2) + r]);
        #pragma unroll
        for (int j = 0; j < 4; ++j) {
            float v = acc[j][r] + bvv;
            if (ACT) v = (v >= 0.f) ? v : 0.1f * v;
            vv[j][r] = v;
        }
    }

    if (OUTM == 0) {
        #pragma unroll
        for (int j = 0; j < 4; ++j)
            #pragma unroll
            for (int r = 0; r < 4; ++r) {
                size_t idx = (size_t)(m0 + (wv << 4) + (fg << 2) + r) * ldc
                           + (nbase + n0 + (j << 4) + fr);
                if (OUT_BF16) ((u16*)Cv)[idx] = f2bf(vv[j][r]);
                else          ((float*)Cv)[idx] = vv[j][r];
            }
    } else if (OUTM == 1) {
        __syncthreads();
        u16* bb = smem;                                 // [64 n][72 m]
        #pragma unroll
        for (int j = 0; j < 4; ++j)
            #pragma unroll
            for (int r = 0; r < 4; ++r)
                bb[((j << 4) + fr) * 72 + (wv << 4) + (fg << 2) + r] = f2bf(vv[j][r]);
        __syncthreads();
        int row = t >> 2, seg = (t & 3) << 4;
        const uint4* src = (const uint4*)&bb[row * 72 + seg];
        uint4* dst = (uint4*)((u16*)Cv + (size_t)(nbase + n0 + row) * M + m0 + seg);
        dst[0] = src[0];
        dst[1] = src[1];
    } else {
        // NCHW final: out[b][m][hw]; n-tile never crosses a batch (1536%64==0)
        __syncthreads();
        u16* bb = smem;                                 // [64 m][72 n]
        #pragma unroll
        for (int j = 0; j < 4; ++j)
            #pragma unroll
            for (int r = 0; r < 4; ++r)
                bb[((wv << 4) + (fg << 2) + r) * 72 + (j << 4) + fr] = f2bf(vv[j][r]);
        __syncthreads();
        int f32o = *flag;
        int mrow = t >> 2, seg = (t & 3) << 4;
        int b = n0 / 1536, hw0 = (n0 % 1536) + seg;
        size_t base = (size_t)(b * 128 + m0 + mrow) * 1536 + hw0;
        if (!f32o) {
            const uint4* src = (const uint4*)&bb[mrow * 72 + seg];
            uint4* dst = (uint4*)((u16*)Cv + base);
            dst[0] = src[0];
            dst[1] = src[1];
        } else {
            float* dst = (float*)Cv + base;
            #pragma unroll
            for (int j = 0; j < 16; ++j) dst[j] = bf2f(bb[mrow * 72 + seg + j]);
        }
    }
}

// ---------------------------------------------------------------------------
// Implicit-GEMM 3x3 conv (pad 1): C^T[tok][M] = lrelu(AW * X^T + bias)
// Prefetch-pipelined over flattened (tap, k0). POS=1: fuse sine pos-enc add.
// ---------------------------------------------------------------------------
template<int CIN, int POS>
__global__ __launch_bounds__(256) void conv_gemm(
    const u16* __restrict__ A, const u16* __restrict__ X,
    const u16* __restrict__ bias, u16* __restrict__ Cv, int M)
{
    __shared__ __align__(16) u16 smem[5120];
    u16 (*As)[40] = (u16(*)[40])smem;
    u16 (*Bs)[40] = (u16(*)[40])(smem + 2560);

    constexpr int NK  = CIN / 32;      // 4 or 8 (pow2)
    constexpr int TOT = 9 * NK;

    const int t    = threadIdx.x;
    const int wv   = t >> 6, lane = t & 63;
    const int fr   = lane & 15, fg = lane >> 4;
    const int tiles_m = M >> 6;
    const int bm = blockIdx.x % tiles_m, bn = blockIdx.x / tiles_m;
    const int m0 = bm << 6, n0 = bn << 6;

    const int srow = t >> 2;
    const int scol = (t & 3) << 3;
    const int n  = n0 + srow;
    const int hw = n % 1536;
    const int hp = hw / 48, wp = hw % 48;
    const u16* Ar = A + (size_t)(m0 + srow) * (9 * CIN) + scol;

    f32x4 acc[4] = {};

    auto ld = [&](int s, uint4& avo, uint4& bvo) {
        int tap = s / NK, k0 = (s & (NK - 1)) << 5;
        int dy = tap / 3 - 1, dx = tap % 3 - 1;
        bool vr = ((unsigned)(hp + dy) < 32u) && ((unsigned)(wp + dx) < 48u);
        avo = *(const uint4*)(Ar + tap * CIN + k0);
        if (vr) bvo = *(const uint4*)(X + (size_t)(n + dy * 48 + dx) * CIN + scol + k0);
        else    bvo = uint4{0, 0, 0, 0};
    };

    uint4 av, bv;
    ld(0, av, bv);
    for (int s = 0; s < TOT; ++s) {
        __syncthreads();
        *(uint4*)&As[srow][scol] = av;
        *(uint4*)&Bs[srow][scol] = bv;
        __syncthreads();
        uint4 av2 = {0, 0, 0, 0}, bv2 = {0, 0, 0, 0};
        if (s + 1 < TOT) ld(s + 1, av2, bv2);
        union U { uint4 q; s16x8 v; };
        U af; af.q = *(const uint4*)&As[(wv << 4) + fr][fg << 3];
        U bf[4];
        #pragma unroll
        for (int j = 0; j < 4; ++j)
            bf[j].q = *(const uint4*)&Bs[(j << 4) + fr][fg << 3];
        #pragma unroll
        for (int j = 0; j < 4; ++j)
            acc[j] = __builtin_amdgcn_mfma_f32_16x16x32_bf16(af.v, bf[j].v, acc[j], 0, 0, 0);
        av = av2; bv = bv2;
    }

    float vv[4][4];
    #pragma unroll
    for (int r = 0; r < 4; ++r) {
        float bvv = bf2f(bias[m0 + (wv << 4) + (fg << 2) + r]);
        #pragma unroll
        for (int j = 0; j < 4; ++j) {
            float v = acc[j][r] + bvv;
            vv[j][r] = (v >= 0.f) ? v : 0.1f * v;
        }
    }

    if (POS) {
        const float TWO_PI = 6.283185307179586f;
        #pragma unroll
        for (int j = 0; j < 4; ++j) {
            int ntok = n0 + (j << 4) + fr;
            int hw2 = ntok % 1536;
            int hp2 = hw2 / 48, wp2 = hw2 % 48;
            float yv = (float)(hp2 + 1) * (TWO_PI / (32.f + 1e-6f));
            float xv = (float)(wp2 + 1) * (TWO_PI / (48.f + 1e-6f));
            #pragma unroll
            for (int r = 0; r < 4; ++r) {
                int d = m0 + (wv << 4) + (fg << 2) + r;
                int mm = (d & 63) >> 1;
                float dim = exp2f((float)mm * (13.287712379549449f / 32.f));
                float val = ((d < 64) ? yv : xv) / dim;
                vv[j][r] += (d & 1) ? cosf(val) : sinf(val);
            }
        }
    }

    __syncthreads();
    u16* bb = smem;                                     // [64 n][72 m]
    #pragma unroll
    for (int j = 0; j < 4; ++j)
        #pragma unroll
        for (int r = 0; r < 4; ++r)
            bb[((j << 4) + fr) * 72 + (wv << 4) + (fg << 2) + r] = f2bf(vv[j][r]);
    __syncthreads();
    int row = t >> 2, seg = (t & 3) << 4;
    const uint4* src = (const uint4*)&bb[row * 72 + seg];
    uint4* dst = (uint4*)(Cv + (size_t)(n0 + row) * M + m0 + seg);
    dst[0] = src[0];
    dst[1] = src[1];
}

// ---------------------------------------------------------------------------
// conv1 input: X0[b*1536+hw][ci] = feat0_l1[b][ci][hw]  (dual dtype)
// ---------------------------------------------------------------------------
__global__ void xpose_in(const void* __restrict__ src, u16* __restrict__ X0,
                         const int* __restrict__ flag)
{
    int g = blockIdx.x * 256 + threadIdx.x;          // 6144*16
    if (g >= 6144 * 16) return;
    int f32 = *flag;
    int c = g & 127;
    int tok0 = (g >> 7) << 3;
    int b = tok0 / 1536, hw = tok0 % 1536;
    #pragma unroll
    for (int j = 0; j < 8; ++j) {
        float x = ldv(src, (size_t)(b * 128 + c) * 1536 + hw + j, f32);
        X0[(size_t)(tok0 + j) * 128 + c] = f2bf(x);
    }
}

// ---------------------------------------------------------------------------
// cat/value input full batch: CATT[b*7680+n][256]
// ---------------------------------------------------------------------------
__global__ void cat_build(const void* __restrict__ f00, const void* __restrict__ f01,
                          const void* __restrict__ f10, const void* __restrict__ f11,
                          const u16* __restrict__ lvl_emb, u16* __restrict__ CATT,
                          const int* __restrict__ flag)
{
    int g = blockIdx.x * 256 + threadIdx.x;          // 30720*32
    if (g >= 30720 * 32) return;
    int f32 = *flag;
    int tok = g >> 5, c0 = (g & 31) << 3;
    int b = tok / 7680, n = tok % 7680;
    int lvl = (n >= 6144) ? 1 : 0;
    int ns = lvl ? n - 6144 : n;
    int HW = lvl ? 1536 : 6144;
    u16x8 v;
    #pragma unroll
    for (int j = 0; j < 8; ++j) {
        int c = c0 + j, cc = c & 127;
        const void* f = (c < 128) ? (lvl ? f01 : f00) : (lvl ? f11 : f10);
        float x = ldv(f, (size_t)(b * 128 + cc) * HW + ns, f32);
        v[j] = f2bf(x + bf2f(lvl_emb[lvl * 128 + cc]));
    }
    *(u16x8*)(CATT + (size_t)tok * 256 + c0) = v;
}

// ---------------------------------------------------------------------------
// MSDeformAttn sampling (+softmax), vectorized gather, XCD-chunked swizzle:
// consecutive tokens land on the same XCD -> sampling window L2-resident.
// ---------------------------------------------------------------------------
__global__ void msda_sample(const float* __restrict__ PA, const u16* __restrict__ VAL,
                            u16* __restrict__ S)
{
    __shared__ int   SMI[4][64];
    __shared__ float SMW[4][64];
    __shared__ float LG[64];
    __shared__ float EW[64];
    int bid = blockIdx.x;                 // 6144 = 8 * 768
    int tok = ((bid & 7) * 768) + (bid >> 3);
    int t = threadIdx.x;                  // 128
    int b = tok / 1536, hw = tok % 1536;
    int hp = hw / 48, wp = hw % 48;

    if (t < 64) {
        int l = (t >> 3) & 1, p = t & 7, h = t >> 4;
        int orow = h * 32 + l * 16 + p * 2;
        float offx = PA[(size_t)orow * 6144 + tok];
        float offy = PA[(size_t)(orow + 1) * 6144 + tok];
        LG[t]      = PA[(size_t)(128 + h * 16 + l * 8 + p) * 6144 + tok];
        float Wl = l ? 48.f : 96.f, Hl = l ? 32.f : 64.f;
        int iWl = l ? 48 : 96, iHl = l ? 32 : 64;
        int base = l ? 6144 : 0;
        float locx = (wp + 0.5f) / 48.f + offx / Wl;
        float locy = (hp + 0.5f) / 32.f + offy / Hl;
        float x = locx * Wl - 0.5f;
        float y = locy * Hl - 0.5f;
        float xf = floorf(x), yf = floorf(y);
        float fx = x - xf, fy = y - yf;
        int ix = (int)xf, iy = (int)yf;
        int vrow = b * 7680 + base;
        float w00 = (1.f - fx) * (1.f - fy), w01 = fx * (1.f - fy);
        float w10 = (1.f - fx) * fy,         w11 = fx * fy;
        bool vx0 = (ix >= 0) & (ix < iWl),     vx1 = (ix + 1 >= 0) & (ix + 1 < iWl);
        bool vy0 = (iy >= 0) & (iy < iHl),     vy1 = (iy + 1 >= 0) & (iy + 1 < iHl);
        SMI[0][t] = (vx0 & vy0) ? vrow + iy * iWl + ix           : 0;
        SMI[1][t] = (vx1 & vy0) ? vrow + iy * iWl + ix + 1       : 0;
        SMI[2][t] = (vx0 & vy1) ? vrow + (iy + 1) * iWl + ix     : 0;
        SMI[3][t] = (vx1 & vy1) ? vrow + (iy + 1) * iWl + ix + 1 : 0;
        SMW[0][t] = (vx0 & vy0) ? w00 : 0.f;
        SMW[1][t] = (vx1 & vy0) ? w01 : 0.f;
        SMW[2][t] = (vx0 & vy1) ? w10 : 0.f;
        SMW[3][t] = (vx1 & vy1) ? w11 : 0.f;
    }
    __syncthreads();
    if (t < 64) {
        int h0 = t & ~15;
        float mx = -1e30f;
        for (int i = 0; i < 16; ++i) mx = fmaxf(mx, LG[h0 + i]);
        EW[t] = expf(LG[t] - mx);
    }
    __syncthreads();
    if (t < 64) {
        int h0 = t & ~15;
        float s = 0.f;
        for (int i = 0; i < 16; ++i) s += EW[h0 + i];
        float aw = EW[t] / s;
        SMW[0][t] *= aw; SMW[1][t] *= aw; SMW[2][t] *= aw; SMW[3][t] *= aw;
    }
    __syncthreads();

    const int h = t >> 5, sub = t & 31, dseg = sub & 15, half = sub >> 4;
    const u16* Vb = VAL + (size_t)dseg * 8;
    float acc[8] = {0.f, 0.f, 0.f, 0.f, 0.f, 0.f, 0.f, 0.f};
    #pragma unroll 8
    for (int r = 0; r < 32; ++r) {
        int pr = (half << 5) + r;
        int s = pr >> 2, c = pr & 3;
        float w  = SMW[c][(h << 4) + s];
        int  idx = SMI[c][(h << 4) + s];
        u16x8 v = *(const u16x8*)(Vb + (size_t)idx * 128);
        #pragma unroll
        for (int j = 0; j < 8; ++j) acc[j] += w * bf2f(v[j]);
    }
    #pragma unroll
    for (int j = 0; j < 8; ++j) acc[j] += __shfl_xor(acc[j], 16, 64);
    if (!half) {
        u16x8 o;
        #pragma unroll
        for (int j = 0; j < 8; ++j) o[j] = f2bf(acc[j]);
        *(u16x8*)(S + (size_t)tok * 512 + (h << 7) + (dseg << 3)) = o;
    }
}

// ---------------------------------------------------------------------------
extern "C" void kernel_launch(void* const* d_in, const int* in_sizes, int n_in,
                              void* d_out, int out_size, void* d_ws, size_t ws_size,
                              hipStream_t stream)
{
    (void)in_sizes; (void)n_in; (void)out_size; (void)ws_size;

    char* ws = (char*)d_ws;
    size_t off = 0;
    auto alloc = [&](size_t bytes) { size_t o = off; off += (bytes + 255) & ~(size_t)255; return o; };
    int*   FLAG = (int*)(ws + alloc(256));
    u16*   AW1  = (u16*)(ws + alloc(294912ull * 2));
    u16*   AW2  = (u16*)(ws + alloc(294912ull * 2));
    u16*   AW3  = (u16*)(ws + alloc(147456ull * 2));
    u16*   AVW  = (u16*)(ws + alloc(32768ull * 2));
    u16*   APJ0 = (u16*)(ws + alloc(24576ull * 2));
    u16*   APJ1 = (u16*)(ws + alloc(24576ull * 2));
    u16*   AOP0 = (u16*)(ws + alloc(65536ull * 2));
    u16*   AOP1 = (u16*)(ws + alloc(65536ull * 2));
    u16*   BPJ0 = (u16*)(ws + alloc(512));
    u16*   BPJ1 = (u16*)(ws + alloc(512));
    u16*   SB   = (u16*)(ws + alloc(1152ull * 2));
    u16*   VAL  = (u16*)(ws + alloc(30720ull * 128 * 2));
    u16*   X0   = (u16*)(ws + alloc(6144ull * 128 * 2));
    u16*   CH1  = (u16*)(ws + alloc(6144ull * 256 * 2));
    u16*   CH2  = (u16*)(ws + alloc(6144ull * 128 * 2));
    u16*   QT0  = (u16*)(ws + alloc(6144ull * 128 * 2));
    u16*   QT1  = (u16*)(ws + alloc(6144ull * 128 * 2));
    char*  R    = ws + alloc(30720ull * 256 * 2);          // union: CATT | PA+S
    u16*   CATT = (u16*)R;
    float* PA   = (float*)R;
    u16*   S    = (u16*)(R + 192ull * 6144 * 4);

    u16* cb1C = SB + 0;   u16* cb2C = SB + 256;  u16* cb3C = SB + 384;
    u16* vbC  = SB + 512; u16* lvlC = SB + 640;
    u16* ob0C = SB + 896; u16* ob1C = SB + 1024;

    // 0. dtype detect + unified weight prep (raw-input reads)
    detect_dtype<<<1, 256, 0, stream>>>((const unsigned int*)d_in[0], FLAG);
    P21 a;
    const int widx[21] = {4,5,6,7,8,9,10,11,12, 13,14,15,16,17,18, 19,20,21,22,23,24};
    for (int i = 0; i < 21; ++i) a.p[i] = d_in[widx[i]];
    prep_all<<<3718, 256, 0, stream>>>(a, FLAG, AW1, AW2, AW3, AVW,
                                       APJ0, APJ1, AOP0, AOP1, BPJ0, BPJ1, SB);

    // 1. value path (full batch)
    cat_build<<<3840, 256, 0, stream>>>(d_in[0], d_in[1], d_in[2], d_in[3], lvlC, CATT, FLAG);
    gemm_kn<0, 1, 1><<<2 * 480, 256, 0, stream>>>(AVW, CATT, vbC, VAL, 128, 256, 0, 0, FLAG);

    // 2. conv stack (implicit GEMM; conv3 fuses pos-enc)
    xpose_in<<<384, 256, 0, stream>>>(d_in[1], X0, FLAG);
    conv_gemm<128, 0><<<4 * 96, 256, 0, stream>>>(AW1, X0,  cb1C, CH1, 256);
    conv_gemm<256, 0><<<2 * 96, 256, 0, stream>>>(AW2, CH1, cb2C, CH2, 128);
    conv_gemm<128, 1><<<2 * 96, 256, 0, stream>>>(AW3, CH2, cb3C, QT0, 128);

    // 3. attention block 0
    gemm_kn<0, 0, 0><<<3 * 96, 256, 0, stream>>>(APJ0, QT0, BPJ0, PA, 192, 128, 6144, 0, FLAG);
    msda_sample<<<6144, 128, 0, stream>>>(PA, VAL, S);
    gemm_kn<0, 1, 1><<<2 * 96, 256, 0, stream>>>(AOP0, S, ob0C, QT1, 128, 512, 0, 0, FLAG);

    // 4. attention block 1 (final GEMM writes NCHW d_out directly)
    gemm_kn<0, 0, 0><<<3 * 96, 256, 0, stream>>>(APJ1, QT1, BPJ1, PA, 192, 128, 6144, 0, FLAG);
    msda_sample<<<6144, 128, 0, stream>>>(PA, VAL, S);
    gemm_kn<0, 2, 1><<<2 * 96, 256, 0, stream>>>(AOP1, S, ob1C, d_out, 128, 512, 0, 0, FLAG);
}

// Round 5
// 166.597 us; speedup vs baseline: 3.9961x; 1.1899x over previous
//
#include <hip/hip_runtime.h>
#include <hip/hip_bf16.h>

typedef unsigned short u16;
typedef u16   u16x8 __attribute__((ext_vector_type(8)));
typedef short s16x8 __attribute__((ext_vector_type(8)));
typedef float f32x4 __attribute__((ext_vector_type(4)));

__device__ __forceinline__ float bf2f(u16 u) {
    union { unsigned int i; float f; } v; v.i = ((unsigned int)u) << 16; return v.f;
}
__device__ __forceinline__ u16 f2bf(float f) {
    unsigned int x = __float_as_uint(f);
    return (u16)((x + 0x7fffu + ((x >> 16) & 1u)) >> 16);   // RNE
}
__device__ __forceinline__ float ldv(const void* p, size_t i, int f32) {
    return f32 ? ((const float*)p)[i] : bf2f(((const u16*)p)[i]);
}

// ===========================================================================
// GEMM core, BK=64: C = A[M][K] * Bt[N][K]^T (+bias, optional lrelu)
// 64x64 tile, 4 waves, 2 barriers per 64-K (8 MFMA / 10 ds_read_b128 / stage)
// OUTM=0: C[m][nbase+n] (ldc). OUTM=1: C^T[nbase+n][m] bounce. OUTM=2: NCHW out.
// ===========================================================================
template<int ACT, int OUTM, int OUT_BF16>
__device__ __forceinline__ void gemm_body(
    u16* __restrict__ smem, int bid,
    const u16* __restrict__ A, const u16* __restrict__ Bt,
    const u16* __restrict__ bias, void* __restrict__ Cv,
    int M, int K, int ldc, int nbase, const int* __restrict__ flag)
{
    u16 (*As)[72] = (u16(*)[72])smem;                 // [64][72] x2 = 9216 u16
    u16 (*Bs)[72] = (u16(*)[72])(smem + 4608);

    const int t    = threadIdx.x;
    const int wv   = t >> 6, lane = t & 63;
    const int fr   = lane & 15, fg = lane >> 4;
    const int tiles_m = M >> 6;
    const int bm = bid % tiles_m, bn = bid / tiles_m;
    const int m0 = bm << 6, n0 = bn << 6;

    f32x4 acc[4] = {};
    const int srow = t >> 2;
    const int scol = (t & 3) << 4;                    // 0,16,32,48
    const u16* Ap = A  + (size_t)(m0 + srow) * K + scol;
    const u16* Bp = Bt + (size_t)(n0 + srow) * K + scol;

    const int ns = K >> 6;
    uint4 av0 = *(const uint4*)Ap,       av1 = *(const uint4*)(Ap + 8);
    uint4 bv0 = *(const uint4*)Bp,       bv1 = *(const uint4*)(Bp + 8);
    for (int s = 0; s < ns; ++s) {
        __syncthreads();
        *(uint4*)&As[srow][scol]     = av0;  *(uint4*)&As[srow][scol + 8] = av1;
        *(uint4*)&Bs[srow][scol]     = bv0;  *(uint4*)&Bs[srow][scol + 8] = bv1;
        __syncthreads();
        if (s + 1 < ns) {
            const u16* An = Ap + ((s + 1) << 6);
            const u16* Bn = Bp + ((s + 1) << 6);
            av0 = *(const uint4*)An;  av1 = *(const uint4*)(An + 8);
            bv0 = *(const uint4*)Bn;  bv1 = *(const uint4*)(Bn + 8);
        }
        union U { uint4 q; s16x8 v; };
        #pragma unroll
        for (int kk = 0; kk < 2; ++kk) {
            U af; af.q = *(const uint4*)&As[(wv << 4) + fr][(kk << 5) + (fg << 3)];
            U bf[4];
            #pragma unroll
            for (int j = 0; j < 4; ++j)
                bf[j].q = *(const uint4*)&Bs[(j << 4) + fr][(kk << 5) + (fg << 3)];
            #pragma unroll
            for (int j = 0; j < 4; ++j)
                acc[j] = __builtin_amdgcn_mfma_f32_16x16x32_bf16(af.v, bf[j].v, acc[j], 0, 0, 0);
        }
    }

    float vv[4][4];
    #pragma unroll
    for (int r = 0; r < 4; ++r) {
        float bvv = bf2f(bias[m0 + (wv << 4) + (fg << 2) + r]);
        #pragma unroll
        for (int j = 0; j < 4; ++j) {
            float v = acc[j][r] + bvv;
            if (ACT) v = (v >= 0.f) ? v : 0.1f * v;
            vv[j][r] = v;
        }
    }

    if (OUTM == 0) {
        #pragma unroll
        for (int j = 0; j < 4; ++j)
            #pragma unroll
            for (int r = 0; r < 4; ++r) {
                size_t idx = (size_t)(m0 + (wv << 4) + (fg << 2) + r) * ldc
                           + (nbase + n0 + (j << 4) + fr);
                if (OUT_BF16) ((u16*)Cv)[idx] = f2bf(vv[j][r]);
                else          ((float*)Cv)[idx] = vv[j][r];
            }
    } else if (OUTM == 1) {
        __syncthreads();
        u16* bb = smem;                                 // [64 n][72 m]
        #pragma unroll
        for (int j = 0; j < 4; ++j)
            #pragma unroll
            for (int r = 0; r < 4; ++r)
                bb[((j << 4) + fr) * 72 + (wv << 4) + (fg << 2) + r] = f2bf(vv[j][r]);
        __syncthreads();
        int row = t >> 2, seg = (t & 3) << 4;
        const uint4* src = (const uint4*)&bb[row * 72 + seg];
        uint4* dst = (uint4*)((u16*)Cv + (size_t)(nbase + n0 + row) * M + m0 + seg);
        dst[0] = src[0];
        dst[1] = src[1];
    } else {
        // NCHW final: out[b][m][hw]; n-tile never crosses a batch (1536%64==0)
        __syncthreads();
        u16* bb = smem;                                 // [64 m][72 n]
        #pragma unroll
        for (int j = 0; j < 4; ++j)
            #pragma unroll
            for (int r = 0; r < 4; ++r)
                bb[((wv << 4) + (fg << 2) + r) * 72 + (j << 4) + fr] = f2bf(vv[j][r]);
        __syncthreads();
        int f32o = *flag;
        int mrow = t >> 2, seg = (t & 3) << 4;
        int b = n0 / 1536, hw0 = (n0 % 1536) + seg;
        size_t base = (size_t)(b * 128 + m0 + mrow) * 1536 + hw0;
        if (!f32o) {
            const uint4* src = (const uint4*)&bb[mrow * 72 + seg];
            uint4* dst = (uint4*)((u16*)Cv + base);
            dst[0] = src[0];
            dst[1] = src[1];
        } else {
            float* dst = (float*)Cv + base;
            #pragma unroll
            for (int j = 0; j < 16; ++j) dst[j] = bf2f(bb[mrow * 72 + seg + j]);
        }
    }
}

// ===========================================================================
// Implicit-GEMM 3x3 conv (pad 1), BK=64: C^T[tok][M] = lrelu(AW*X^T + bias)
// POS=1 fuses the sine positional encoding into the epilogue.
// ===========================================================================
template<int CIN, int POS>
__device__ __forceinline__ void conv_body(
    u16* __restrict__ smem, int bid,
    const u16* __restrict__ A, const u16* __restrict__ X,
    const u16* __restrict__ bias, u16* __restrict__ Cv, int M)
{
    u16 (*As)[72] = (u16(*)[72])smem;
    u16 (*Bs)[72] = (u16(*)[72])(smem + 4608);

    constexpr int NK2 = CIN / 64;       // 2 or 4
    constexpr int TOT = 9 * NK2;

    const int t    = threadIdx.x;
    const int wv   = t >> 6, lane = t & 63;
    const int fr   = lane & 15, fg = lane >> 4;
    const int tiles_m = M >> 6;
    const int bm = bid % tiles_m, bn = bid / tiles_m;
    const int m0 = bm << 6, n0 = bn << 6;

    const int srow = t >> 2;
    const int scol = (t & 3) << 4;
    const int n  = n0 + srow;
    const int hw = n % 1536;
    const int hp = hw / 48, wp = hw % 48;
    const u16* Ar = A + (size_t)(m0 + srow) * (9 * CIN) + scol;

    f32x4 acc[4] = {};

    auto ld = [&](int s, uint4& a0, uint4& a1, uint4& b0, uint4& b1) {
        int tap = s / NK2, k0 = (s % NK2) << 6;
        int dy = tap / 3 - 1, dx = tap % 3 - 1;
        bool vr = ((unsigned)(hp + dy) < 32u) && ((unsigned)(wp + dx) < 48u);
        const u16* Ap = Ar + tap * CIN + k0;
        a0 = *(const uint4*)Ap;  a1 = *(const uint4*)(Ap + 8);
        if (vr) {
            const u16* Bp = X + (size_t)(n + dy * 48 + dx) * CIN + scol + k0;
            b0 = *(const uint4*)Bp;  b1 = *(const uint4*)(Bp + 8);
        } else {
            b0 = uint4{0,0,0,0};  b1 = uint4{0,0,0,0};
        }
    };

    uint4 av0, av1, bv0, bv1;
    ld(0, av0, av1, bv0, bv1);
    for (int s = 0; s < TOT; ++s) {
        __syncthreads();
        *(uint4*)&As[srow][scol]     = av0;  *(uint4*)&As[srow][scol + 8] = av1;
        *(uint4*)&Bs[srow][scol]     = bv0;  *(uint4*)&Bs[srow][scol + 8] = bv1;
        __syncthreads();
        if (s + 1 < TOT) ld(s + 1, av0, av1, bv0, bv1);
        union U { uint4 q; s16x8 v; };
        #pragma unroll
        for (int kk = 0; kk < 2; ++kk) {
            U af; af.q = *(const uint4*)&As[(wv << 4) + fr][(kk << 5) + (fg << 3)];
            U bf[4];
            #pragma unroll
            for (int j = 0; j < 4; ++j)
                bf[j].q = *(const uint4*)&Bs[(j << 4) + fr][(kk << 5) + (fg << 3)];
            #pragma unroll
            for (int j = 0; j < 4; ++j)
                acc[j] = __builtin_amdgcn_mfma_f32_16x16x32_bf16(af.v, bf[j].v, acc[j], 0, 0, 0);
        }
    }

    float vv[4][4];
    #pragma unroll
    for (int r = 0; r < 4; ++r) {
        float bvv = bf2f(bias[m0 + (wv << 4) + (fg << 2) + r]);
        #pragma unroll
        for (int j = 0; j < 4; ++j) {
            float v = acc[j][r] + bvv;
            vv[j][r] = (v >= 0.f) ? v : 0.1f * v;
        }
    }

    if (POS) {
        const float TWO_PI = 6.283185307179586f;
        #pragma unroll
        for (int j = 0; j < 4; ++j) {
            int ntok = n0 + (j << 4) + fr;
            int hw2 = ntok % 1536;
            int hp2 = hw2 / 48, wp2 = hw2 % 48;
            float yv = (float)(hp2 + 1) * (TWO_PI / (32.f + 1e-6f));
            float xv = (float)(wp2 + 1) * (TWO_PI / (48.f + 1e-6f));
            #pragma unroll
            for (int r = 0; r < 4; ++r) {
                int d = m0 + (wv << 4) + (fg << 2) + r;
                int mm = (d & 63) >> 1;
                float dim = exp2f((float)mm * (13.287712379549449f / 32.f));
                float val = ((d < 64) ? yv : xv) / dim;
                vv[j][r] += (d & 1) ? cosf(val) : sinf(val);
            }
        }
    }

    __syncthreads();
    u16* bb = smem;                                     // [64 n][72 m]
    #pragma unroll
    for (int j = 0; j < 4; ++j)
        #pragma unroll
        for (int r = 0; r < 4; ++r)
            bb[((j << 4) + fr) * 72 + (wv << 4) + (fg << 2) + r] = f2bf(vv[j][r]);
    __syncthreads();
    int row = t >> 2, seg = (t & 3) << 4;
    const uint4* src = (const uint4*)&bb[row * 72 + seg];
    uint4* dst = (uint4*)(Cv + (size_t)(n0 + row) * M + m0 + seg);
    dst[0] = src[0];
    dst[1] = src[1];
}

// ---------------------------------------------------------------------------
template<int ACT, int OUTM, int OUT_BF16>
__global__ __launch_bounds__(256) void gemm_kn(
    const u16* __restrict__ A, const u16* __restrict__ Bt,
    const u16* __restrict__ bias, void* __restrict__ Cv,
    int M, int K, int ldc, int nbase, const int* __restrict__ flag)
{
    __shared__ __align__(16) u16 smem[9216];
    gemm_body<ACT, OUTM, OUT_BF16>(smem, blockIdx.x, A, Bt, bias, Cv, M, K, ldc, nbase, flag);
}

template<int CIN, int POS>
__global__ __launch_bounds__(256) void conv_gemm(
    const u16* __restrict__ A, const u16* __restrict__ X,
    const u16* __restrict__ bias, u16* __restrict__ Cv, int M)
{
    __shared__ __align__(16) u16 smem[9216];
    conv_body<CIN, POS>(smem, blockIdx.x, A, X, bias, Cv, M);
}

// fat kernel: value GEMM (960 blocks) || conv1 (384 blocks) — independent work
__global__ __launch_bounds__(256) void val_conv1_k(
    const u16* __restrict__ AVW, const u16* __restrict__ CATT,
    const u16* __restrict__ vb, u16* __restrict__ VAL,
    const u16* __restrict__ AW1, const u16* __restrict__ X0,
    const u16* __restrict__ cb1, u16* __restrict__ CH1)
{
    __shared__ __align__(16) u16 smem[9216];
    int bid = blockIdx.x;
    if (bid < 960) gemm_body<0, 1, 1>(smem, bid, AVW, CATT, vb, VAL, 128, 256, 0, 0, nullptr);
    else           conv_body<128, 0>(smem, bid - 960, AW1, X0, cb1, CH1, 256);
}

// ===========================================================================
// fused prep: per-block inline dtype detect; then one of
//   [0,3718)            : weight canon/transpose  (951808 elems)
//   [3718,7558)         : cat_build               (983040 elems)
//   [7558,7942)         : xpose_in                (98304 elems)
// block 0 also publishes FLAG for later dispatches.
// ===========================================================================
struct P21 { const void* p[21]; };
// p[]: 0 cw1,1 cb1,2 cw2,3 cb2,4 cw3,5 cb3,6 vw,7 vb,8 lvl,
//      9 sw0,10 sb0,11 aw0,12 ab0,13 ow0,14 ob0, 15 sw1,16 sb1,17 aw1,18 ab1,19 ow1,20 ob1

__global__ __launch_bounds__(256) void prep_fused(
    P21 a, const void* __restrict__ f00, const void* __restrict__ f01,
    const void* __restrict__ f10, const void* __restrict__ f11,
    int* __restrict__ FLAG,
    u16* AW1, u16* AW2, u16* AW3, u16* AVW,
    u16* APJ0, u16* APJ1, u16* AOP0, u16* AOP1,
    u16* BPJ0, u16* BPJ1, u16* SB,
    u16* CATT, u16* X0)
{
    const int t = threadIdx.x;
    // inline dtype detect (all blocks, from f00's first 1 KB — L2-broadcast)
    unsigned int w = ((const unsigned int*)f00)[t];
    float pa = fabsf(bf2f((u16)(w & 0xFFFFu)));
    int cnt = __syncthreads_count(pa > 1e-6f && pa < 1e4f);
    const int f32 = (cnt < 128);
    const int bid = blockIdx.x;
    if (bid == 0 && t == 0) *FLAG = f32;

    if (bid < 3718) {
        int g = bid * 256 + t;
        if (g < 294912) { int m = g / 1152, rem = g % 1152, tap = rem >> 7, ci = rem & 127;
            AW1[g] = f2bf(ldv(a.p[0], (size_t)m * 1152 + ci * 9 + tap, f32)); return; }
        g -= 294912;
        if (g < 294912) { int m = g / 2304, rem = g % 2304, tap = rem >> 8, ci = rem & 255;
            AW2[g] = f2bf(ldv(a.p[2], (size_t)m * 2304 + ci * 9 + tap, f32)); return; }
        g -= 294912;
        if (g < 147456) { int m = g / 1152, rem = g % 1152, tap = rem >> 7, ci = rem & 127;
            AW3[g] = f2bf(ldv(a.p[4], (size_t)m * 1152 + ci * 9 + tap, f32)); return; }
        g -= 147456;
        if (g < 32768) { AVW[g] = f2bf(ldv(a.p[6], g, f32)); return; }
        g -= 32768;
        if (g < 24576) { int o = g >> 7, d = g & 127;
            APJ0[g] = f2bf(o < 128 ? ldv(a.p[9], d * 128 + o, f32)
                                   : ldv(a.p[11], d * 64 + (o - 128), f32)); return; }
        g -= 24576;
        if (g < 24576) { int o = g >> 7, d = g & 127;
            APJ1[g] = f2bf(o < 128 ? ldv(a.p[15], d * 128 + o, f32)
                                   : ldv(a.p[17], d * 64 + (o - 128), f32)); return; }
        g -= 24576;
        if (g < 65536) { int o = g >> 9, k = g & 511; AOP0[g] = f2bf(ldv(a.p[13], k * 128 + o, f32)); return; }
        g -= 65536;
        if (g < 65536) { int o = g >> 9, k = g & 511; AOP1[g] = f2bf(ldv(a.p[19], k * 128 + o, f32)); return; }
        g -= 65536;
        if (g < 192) { BPJ0[g] = f2bf(g < 128 ? ldv(a.p[10], g, f32) : ldv(a.p[12], g - 128, f32)); return; }
        g -= 192;
        if (g < 192) { BPJ1[g] = f2bf(g < 128 ? ldv(a.p[16], g, f32) : ldv(a.p[18], g - 128, f32)); return; }
        g -= 192;
        if (g < 1152) {
            const int off[8] = {0, 256, 384, 512, 640, 896, 1024, 1152};
            const int src[7] = {1, 3, 5, 7, 8, 14, 20};
            int s = 0;
            #pragma unroll
            for (int i = 1; i < 7; ++i) s += (g >= off[i]);
            SB[g] = f2bf(ldv(a.p[src[s]], g - off[s], f32));
        }
        return;
    }
    if (bid < 7558) {
        int g = (bid - 3718) * 256 + t;                // cat_build
        int tok = g >> 5, c0 = (g & 31) << 3;
        int b = tok / 7680, n = tok % 7680;
        int lvl = (n >= 6144) ? 1 : 0;
        int ns = lvl ? n - 6144 : n;
        int HW = lvl ? 1536 : 6144;
        u16x8 v;
        #pragma unroll
        for (int j = 0; j < 8; ++j) {
            int c = c0 + j, cc = c & 127;
            const void* f = (c < 128) ? (lvl ? f01 : f00) : (lvl ? f11 : f10);
            float x = ldv(f, (size_t)(b * 128 + cc) * HW + ns, f32);
            // lvl_emb add: read raw (a.p[8]) to avoid dependency on SB
            v[j] = f2bf(x + ldv(a.p[8], lvl * 128 + cc, f32));
        }
        *(u16x8*)(CATT + (size_t)tok * 256 + c0) = v;
        return;
    }
    {
        int g = (bid - 7558) * 256 + t;                // xpose_in
        int c = g & 127;
        int tok0 = (g >> 7) << 3;
        int b = tok0 / 1536, hw = tok0 % 1536;
        #pragma unroll
        for (int j = 0; j < 8; ++j) {
            float x = ldv(f01, (size_t)(b * 128 + c) * 1536 + hw + j, f32);
            X0[(size_t)(tok0 + j) * 128 + c] = f2bf(x);
        }
    }
}

// ===========================================================================
// MSDeformAttn sampling (+softmax), vectorized gather, XCD-chunked swizzle
// ===========================================================================
__global__ void msda_sample(const float* __restrict__ PA, const u16* __restrict__ VAL,
                            u16* __restrict__ S)
{
    __shared__ int   SMI[4][64];
    __shared__ float SMW[4][64];
    __shared__ float LG[64];
    __shared__ float EW[64];
    int bid = blockIdx.x;                 // 6144 = 8 * 768
    int tok = ((bid & 7) * 768) + (bid >> 3);
    int t = threadIdx.x;                  // 128
    int b = tok / 1536, hw = tok % 1536;
    int hp = hw / 48, wp = hw % 48;

    if (t < 64) {
        int l = (t >> 3) & 1, p = t & 7, h = t >> 4;
        int orow = h * 32 + l * 16 + p * 2;
        float offx = PA[(size_t)orow * 6144 + tok];
        float offy = PA[(size_t)(orow + 1) * 6144 + tok];
        LG[t]      = PA[(size_t)(128 + h * 16 + l * 8 + p) * 6144 + tok];
        float Wl = l ? 48.f : 96.f, Hl = l ? 32.f : 64.f;
        int iWl = l ? 48 : 96, iHl = l ? 32 : 64;
        int base = l ? 6144 : 0;
        float locx = (wp + 0.5f) / 48.f + offx / Wl;
        float locy = (hp + 0.5f) / 32.f + offy / Hl;
        float x = locx * Wl - 0.5f;
        float y = locy * Hl - 0.5f;
        float xf = floorf(x), yf = floorf(y);
        float fx = x - xf, fy = y - yf;
        int ix = (int)xf, iy = (int)yf;
        int vrow = b * 7680 + base;
        float w00 = (1.f - fx) * (1.f - fy), w01 = fx * (1.f - fy);
        float w10 = (1.f - fx) * fy,         w11 = fx * fy;
        bool vx0 = (ix >= 0) & (ix < iWl),     vx1 = (ix + 1 >= 0) & (ix + 1 < iWl);
        bool vy0 = (iy >= 0) & (iy < iHl),     vy1 = (iy + 1 >= 0) & (iy + 1 < iHl);
        SMI[0][t] = (vx0 & vy0) ? vrow + iy * iWl + ix           : 0;
        SMI[1][t] = (vx1 & vy0) ? vrow + iy * iWl + ix + 1       : 0;
        SMI[2][t] = (vx0 & vy1) ? vrow + (iy + 1) * iWl + ix     : 0;
        SMI[3][t] = (vx1 & vy1) ? vrow + (iy + 1) * iWl + ix + 1 : 0;
        SMW[0][t] = (vx0 & vy0) ? w00 : 0.f;
        SMW[1][t] = (vx1 & vy0) ? w01 : 0.f;
        SMW[2][t] = (vx0 & vy1) ? w10 : 0.f;
        SMW[3][t] = (vx1 & vy1) ? w11 : 0.f;
    }
    __syncthreads();
    if (t < 64) {
        int h0 = t & ~15;
        float mx = -1e30f;
        for (int i = 0; i < 16; ++i) mx = fmaxf(mx, LG[h0 + i]);
        EW[t] = expf(LG[t] - mx);
    }
    __syncthreads();
    if (t < 64) {
        int h0 = t & ~15;
        float s = 0.f;
        for (int i = 0; i < 16; ++i) s += EW[h0 + i];
        float aw = EW[t] / s;
        SMW[0][t] *= aw; SMW[1][t] *= aw; SMW[2][t] *= aw; SMW[3][t] *= aw;
    }
    __syncthreads();

    const int h = t >> 5, sub = t & 31, dseg = sub & 15, half = sub >> 4;
    const u16* Vb = VAL + (size_t)dseg * 8;
    float acc[8] = {0.f, 0.f, 0.f, 0.f, 0.f, 0.f, 0.f, 0.f};
    #pragma unroll 8
    for (int r = 0; r < 32; ++r) {
        int pr = (half << 5) + r;
        int s = pr >> 2, c = pr & 3;
        float w  = SMW[c][(h << 4) + s];
        int  idx = SMI[c][(h << 4) + s];
        u16x8 v = *(const u16x8*)(Vb + (size_t)idx * 128);
        #pragma unroll
        for (int j = 0; j < 8; ++j) acc[j] += w * bf2f(v[j]);
    }
    #pragma unroll
    for (int j = 0; j < 8; ++j) acc[j] += __shfl_xor(acc[j], 16, 64);
    if (!half) {
        u16x8 o;
        #pragma unroll
        for (int j = 0; j < 8; ++j) o[j] = f2bf(acc[j]);
        *(u16x8*)(S + (size_t)tok * 512 + (h << 7) + (dseg << 3)) = o;
    }
}

// ---------------------------------------------------------------------------
extern "C" void kernel_launch(void* const* d_in, const int* in_sizes, int n_in,
                              void* d_out, int out_size, void* d_ws, size_t ws_size,
                              hipStream_t stream)
{
    (void)in_sizes; (void)n_in; (void)out_size; (void)ws_size;

    char* ws = (char*)d_ws;
    size_t off = 0;
    auto alloc = [&](size_t bytes) { size_t o = off; off += (bytes + 255) & ~(size_t)255; return o; };
    int*   FLAG = (int*)(ws + alloc(256));
    u16*   AW1  = (u16*)(ws + alloc(294912ull * 2));
    u16*   AW2  = (u16*)(ws + alloc(294912ull * 2));
    u16*   AW3  = (u16*)(ws + alloc(147456ull * 2));
    u16*   AVW  = (u16*)(ws + alloc(32768ull * 2));
    u16*   APJ0 = (u16*)(ws + alloc(24576ull * 2));
    u16*   APJ1 = (u16*)(ws + alloc(24576ull * 2));
    u16*   AOP0 = (u16*)(ws + alloc(65536ull * 2));
    u16*   AOP1 = (u16*)(ws + alloc(65536ull * 2));
    u16*   BPJ0 = (u16*)(ws + alloc(512));
    u16*   BPJ1 = (u16*)(ws + alloc(512));
    u16*   SB   = (u16*)(ws + alloc(1152ull * 2));
    u16*   VAL  = (u16*)(ws + alloc(30720ull * 128 * 2));
    u16*   X0   = (u16*)(ws + alloc(6144ull * 128 * 2));
    u16*   CH1  = (u16*)(ws + alloc(6144ull * 256 * 2));
    u16*   CH2  = (u16*)(ws + alloc(6144ull * 128 * 2));
    u16*   QT0  = (u16*)(ws + alloc(6144ull * 128 * 2));
    u16*   QT1  = (u16*)(ws + alloc(6144ull * 128 * 2));
    char*  R    = ws + alloc(30720ull * 256 * 2);          // union: CATT | PA+S
    u16*   CATT = (u16*)R;
    float* PA   = (float*)R;
    u16*   S    = (u16*)(R + 192ull * 6144 * 4);

    u16* cb1C = SB + 0;   u16* cb2C = SB + 256;  u16* cb3C = SB + 384;
    u16* vbC  = SB + 512;
    u16* ob0C = SB + 896; u16* ob1C = SB + 1024;

    P21 a;
    const int widx[21] = {4,5,6,7,8,9,10,11,12, 13,14,15,16,17,18, 19,20,21,22,23,24};
    for (int i = 0; i < 21; ++i) a.p[i] = d_in[widx[i]];

    // 1. fused prep: weights + CATT + X0 (+FLAG publish)
    prep_fused<<<7942, 256, 0, stream>>>(a, d_in[0], d_in[1], d_in[2], d_in[3], FLAG,
                                         AW1, AW2, AW3, AVW,
                                         APJ0, APJ1, AOP0, AOP1, BPJ0, BPJ1, SB,
                                         CATT, X0);

    // 2. value GEMM || conv1 (fat kernel, independent grids)
    val_conv1_k<<<960 + 384, 256, 0, stream>>>(AVW, CATT, vbC, VAL, AW1, X0, cb1C, CH1);

    // 3. conv2, conv3(+pos)
    conv_gemm<256, 0><<<2 * 96, 256, 0, stream>>>(AW2, CH1, cb2C, CH2, 128);
    conv_gemm<128, 1><<<2 * 96, 256, 0, stream>>>(AW3, CH2, cb3C, QT0, 128);

    // 4. attention block 0
    gemm_kn<0, 0, 0><<<3 * 96, 256, 0, stream>>>(APJ0, QT0, BPJ0, PA, 192, 128, 6144, 0, FLAG);
    msda_sample<<<6144, 128, 0, stream>>>(PA, VAL, S);
    gemm_kn<0, 1, 1><<<2 * 96, 256, 0, stream>>>(AOP0, S, ob0C, QT1, 128, 512, 0, 0, FLAG);

    // 5. attention block 1 (final GEMM writes NCHW d_out directly)
    gemm_kn<0, 0, 0><<<3 * 96, 256, 0, stream>>>(APJ1, QT1, BPJ1, PA, 192, 128, 6144, 0, FLAG);
    msda_sample<<<6144, 128, 0, stream>>>(PA, VAL, S);
    gemm_kn<0, 2, 1><<<2 * 96, 256, 0, stream>>>(AOP1, S, ob1C, d_out, 128, 512, 0, 0, FLAG);
}

// Round 6
// 153.792 us; speedup vs baseline: 4.3288x; 1.0833x over previous
//
#include <hip/hip_runtime.h>
#include <hip/hip_bf16.h>

typedef unsigned short u16;
typedef u16   u16x8 __attribute__((ext_vector_type(8)));
typedef short s16x8 __attribute__((ext_vector_type(8)));
typedef float f32x4 __attribute__((ext_vector_type(4)));

__device__ __forceinline__ float bf2f(u16 u) {
    union { unsigned int i; float f; } v; v.i = ((unsigned int)u) << 16; return v.f;
}
__device__ __forceinline__ u16 f2bf(float f) {
    unsigned int x = __float_as_uint(f);
    return (u16)((x + 0x7fffu + ((x >> 16) & 1u)) >> 16);   // RNE
}
__device__ __forceinline__ float ldv(const void* p, size_t i, int f32) {
    return f32 ? ((const float*)p)[i] : bf2f(((const u16*)p)[i]);
}

// ===========================================================================
// GEMM core, BK=64: C = A[M][K] * Bt[N][K]^T (+bias, optional lrelu)
// 64x64 tile, 4 waves, 2 barriers per 64-K (8 MFMA / 10 ds_read_b128 / stage)
// OUTM=0: C[m][nbase+n] (ldc). OUTM=1: C^T[nbase+n][m] bounce. OUTM=2: NCHW out.
// ===========================================================================
template<int ACT, int OUTM, int OUT_BF16>
__device__ __forceinline__ void gemm_body(
    u16* __restrict__ smem, int bid,
    const u16* __restrict__ A, const u16* __restrict__ Bt,
    const u16* __restrict__ bias, void* __restrict__ Cv,
    int M, int K, int ldc, int nbase, const int* __restrict__ flag)
{
    u16 (*As)[72] = (u16(*)[72])smem;                 // [64][72] x2 = 9216 u16
    u16 (*Bs)[72] = (u16(*)[72])(smem + 4608);

    const int t    = threadIdx.x;
    const int wv   = t >> 6, lane = t & 63;
    const int fr   = lane & 15, fg = lane >> 4;
    const int tiles_m = M >> 6;
    const int bm = bid % tiles_m, bn = bid / tiles_m;
    const int m0 = bm << 6, n0 = bn << 6;

    f32x4 acc[4] = {};
    const int srow = t >> 2;
    const int scol = (t & 3) << 4;                    // 0,16,32,48
    const u16* Ap = A  + (size_t)(m0 + srow) * K + scol;
    const u16* Bp = Bt + (size_t)(n0 + srow) * K + scol;

    const int ns = K >> 6;
    uint4 av0 = *(const uint4*)Ap,       av1 = *(const uint4*)(Ap + 8);
    uint4 bv0 = *(const uint4*)Bp,       bv1 = *(const uint4*)(Bp + 8);
    for (int s = 0; s < ns; ++s) {
        __syncthreads();
        *(uint4*)&As[srow][scol]     = av0;  *(uint4*)&As[srow][scol + 8] = av1;
        *(uint4*)&Bs[srow][scol]     = bv0;  *(uint4*)&Bs[srow][scol + 8] = bv1;
        __syncthreads();
        if (s + 1 < ns) {
            const u16* An = Ap + ((s + 1) << 6);
            const u16* Bn = Bp + ((s + 1) << 6);
            av0 = *(const uint4*)An;  av1 = *(const uint4*)(An + 8);
            bv0 = *(const uint4*)Bn;  bv1 = *(const uint4*)(Bn + 8);
        }
        union U { uint4 q; s16x8 v; };
        #pragma unroll
        for (int kk = 0; kk < 2; ++kk) {
            U af; af.q = *(const uint4*)&As[(wv << 4) + fr][(kk << 5) + (fg << 3)];
            U bf[4];
            #pragma unroll
            for (int j = 0; j < 4; ++j)
                bf[j].q = *(const uint4*)&Bs[(j << 4) + fr][(kk << 5) + (fg << 3)];
            #pragma unroll
            for (int j = 0; j < 4; ++j)
                acc[j] = __builtin_amdgcn_mfma_f32_16x16x32_bf16(af.v, bf[j].v, acc[j], 0, 0, 0);
        }
    }

    float vv[4][4];
    #pragma unroll
    for (int r = 0; r < 4; ++r) {
        float bvv = bf2f(bias[m0 + (wv << 4) + (fg << 2) + r]);
        #pragma unroll
        for (int j = 0; j < 4; ++j) {
            float v = acc[j][r] + bvv;
            if (ACT) v = (v >= 0.f) ? v : 0.1f * v;
            vv[j][r] = v;
        }
    }

    if (OUTM == 0) {
        #pragma unroll
        for (int j = 0; j < 4; ++j)
            #pragma unroll
            for (int r = 0; r < 4; ++r) {
                size_t idx = (size_t)(m0 + (wv << 4) + (fg << 2) + r) * ldc
                           + (nbase + n0 + (j << 4) + fr);
                if (OUT_BF16) ((u16*)Cv)[idx] = f2bf(vv[j][r]);
                else          ((float*)Cv)[idx] = vv[j][r];
            }
    } else if (OUTM == 1) {
        __syncthreads();
        u16* bb = smem;                                 // [64 n][72 m]
        #pragma unroll
        for (int j = 0; j < 4; ++j)
            #pragma unroll
            for (int r = 0; r < 4; ++r)
                bb[((j << 4) + fr) * 72 + (wv << 4) + (fg << 2) + r] = f2bf(vv[j][r]);
        __syncthreads();
        int row = t >> 2, seg = (t & 3) << 4;
        const uint4* src = (const uint4*)&bb[row * 72 + seg];
        uint4* dst = (uint4*)((u16*)Cv + (size_t)(nbase + n0 + row) * M + m0 + seg);
        dst[0] = src[0];
        dst[1] = src[1];
    } else {
        // NCHW final: out[b][m][hw]; n-tile never crosses a batch (1536%64==0)
        __syncthreads();
        u16* bb = smem;                                 // [64 m][72 n]
        #pragma unroll
        for (int j = 0; j < 4; ++j)
            #pragma unroll
            for (int r = 0; r < 4; ++r)
                bb[((wv << 4) + (fg << 2) + r) * 72 + (j << 4) + fr] = f2bf(vv[j][r]);
        __syncthreads();
        int f32o = *flag;
        int mrow = t >> 2, seg = (t & 3) << 4;
        int b = n0 / 1536, hw0 = (n0 % 1536) + seg;
        size_t base = (size_t)(b * 128 + m0 + mrow) * 1536 + hw0;
        if (!f32o) {
            const uint4* src = (const uint4*)&bb[mrow * 72 + seg];
            uint4* dst = (uint4*)((u16*)Cv + base);
            dst[0] = src[0];
            dst[1] = src[1];
        } else {
            float* dst = (float*)Cv + base;
            #pragma unroll
            for (int j = 0; j < 16; ++j) dst[j] = bf2f(bb[mrow * 72 + seg + j]);
        }
    }
}

// ===========================================================================
// Implicit-GEMM 3x3 conv (pad 1), BK=64: C^T[tok][M] = lrelu(AW*X^T + bias)
// POS=1 fuses the sine positional encoding into the epilogue.
// ===========================================================================
template<int CIN, int POS>
__device__ __forceinline__ void conv_body(
    u16* __restrict__ smem, int bid,
    const u16* __restrict__ A, const u16* __restrict__ X,
    const u16* __restrict__ bias, u16* __restrict__ Cv, int M)
{
    u16 (*As)[72] = (u16(*)[72])smem;
    u16 (*Bs)[72] = (u16(*)[72])(smem + 4608);

    constexpr int NK2 = CIN / 64;       // 2 or 4
    constexpr int TOT = 9 * NK2;

    const int t    = threadIdx.x;
    const int wv   = t >> 6, lane = t & 63;
    const int fr   = lane & 15, fg = lane >> 4;
    const int tiles_m = M >> 6;
    const int bm = bid % tiles_m, bn = bid / tiles_m;
    const int m0 = bm << 6, n0 = bn << 6;

    const int srow = t >> 2;
    const int scol = (t & 3) << 4;
    const int n  = n0 + srow;
    const int hw = n % 1536;
    const int hp = hw / 48, wp = hw % 48;
    const u16* Ar = A + (size_t)(m0 + srow) * (9 * CIN) + scol;

    f32x4 acc[4] = {};

    auto ld = [&](int s, uint4& a0, uint4& a1, uint4& b0, uint4& b1) {
        int tap = s / NK2, k0 = (s % NK2) << 6;
        int dy = tap / 3 - 1, dx = tap % 3 - 1;
        bool vr = ((unsigned)(hp + dy) < 32u) && ((unsigned)(wp + dx) < 48u);
        const u16* Ap = Ar + tap * CIN + k0;
        a0 = *(const uint4*)Ap;  a1 = *(const uint4*)(Ap + 8);
        if (vr) {
            const u16* Bp = X + (size_t)(n + dy * 48 + dx) * CIN + scol + k0;
            b0 = *(const uint4*)Bp;  b1 = *(const uint4*)(Bp + 8);
        } else {
            b0 = uint4{0,0,0,0};  b1 = uint4{0,0,0,0};
        }
    };

    uint4 av0, av1, bv0, bv1;
    ld(0, av0, av1, bv0, bv1);
    for (int s = 0; s < TOT; ++s) {
        __syncthreads();
        *(uint4*)&As[srow][scol]     = av0;  *(uint4*)&As[srow][scol + 8] = av1;
        *(uint4*)&Bs[srow][scol]     = bv0;  *(uint4*)&Bs[srow][scol + 8] = bv1;
        __syncthreads();
        if (s + 1 < TOT) ld(s + 1, av0, av1, bv0, bv1);
        union U { uint4 q; s16x8 v; };
        #pragma unroll
        for (int kk = 0; kk < 2; ++kk) {
            U af; af.q = *(const uint4*)&As[(wv << 4) + fr][(kk << 5) + (fg << 3)];
            U bf[4];
            #pragma unroll
            for (int j = 0; j < 4; ++j)
                bf[j].q = *(const uint4*)&Bs[(j << 4) + fr][(kk << 5) + (fg << 3)];
            #pragma unroll
            for (int j = 0; j < 4; ++j)
                acc[j] = __builtin_amdgcn_mfma_f32_16x16x32_bf16(af.v, bf[j].v, acc[j], 0, 0, 0);
        }
    }

    float vv[4][4];
    #pragma unroll
    for (int r = 0; r < 4; ++r) {
        float bvv = bf2f(bias[m0 + (wv << 4) + (fg << 2) + r]);
        #pragma unroll
        for (int j = 0; j < 4; ++j) {
            float v = acc[j][r] + bvv;
            vv[j][r] = (v >= 0.f) ? v : 0.1f * v;
        }
    }

    if (POS) {
        const float TWO_PI = 6.283185307179586f;
        #pragma unroll
        for (int j = 0; j < 4; ++j) {
            int ntok = n0 + (j << 4) + fr;
            int hw2 = ntok % 1536;
            int hp2 = hw2 / 48, wp2 = hw2 % 48;
            float yv = (float)(hp2 + 1) * (TWO_PI / (32.f + 1e-6f));
            float xv = (float)(wp2 + 1) * (TWO_PI / (48.f + 1e-6f));
            #pragma unroll
            for (int r = 0; r < 4; ++r) {
                int d = m0 + (wv << 4) + (fg << 2) + r;
                int mm = (d & 63) >> 1;
                float dim = exp2f((float)mm * (13.287712379549449f / 32.f));
                float val = ((d < 64) ? yv : xv) / dim;
                vv[j][r] += (d & 1) ? cosf(val) : sinf(val);
            }
        }
    }

    __syncthreads();
    u16* bb = smem;                                     // [64 n][72 m]
    #pragma unroll
    for (int j = 0; j < 4; ++j)
        #pragma unroll
        for (int r = 0; r < 4; ++r)
            bb[((j << 4) + fr) * 72 + (wv << 4) + (fg << 2) + r] = f2bf(vv[j][r]);
    __syncthreads();
    int row = t >> 2, seg = (t & 3) << 4;
    const uint4* src = (const uint4*)&bb[row * 72 + seg];
    uint4* dst = (uint4*)(Cv + (size_t)(n0 + row) * M + m0 + seg);
    dst[0] = src[0];
    dst[1] = src[1];
}

// ---------------------------------------------------------------------------
template<int ACT, int OUTM, int OUT_BF16>
__global__ __launch_bounds__(256) void gemm_kn(
    const u16* __restrict__ A, const u16* __restrict__ Bt,
    const u16* __restrict__ bias, void* __restrict__ Cv,
    int M, int K, int ldc, int nbase, const int* __restrict__ flag)
{
    __shared__ __align__(16) u16 smem[9216];
    gemm_body<ACT, OUTM, OUT_BF16>(smem, blockIdx.x, A, Bt, bias, Cv, M, K, ldc, nbase, flag);
}

template<int CIN, int POS>
__global__ __launch_bounds__(256) void conv_gemm(
    const u16* __restrict__ A, const u16* __restrict__ X,
    const u16* __restrict__ bias, u16* __restrict__ Cv, int M)
{
    __shared__ __align__(16) u16 smem[9216];
    conv_body<CIN, POS>(smem, blockIdx.x, A, X, bias, Cv, M);
}

// fat kernel: value GEMM (960 blocks) || conv1 (384 blocks) — independent work
__global__ __launch_bounds__(256) void val_conv1_k(
    const u16* __restrict__ AVW, const u16* __restrict__ CATT,
    const u16* __restrict__ vb, u16* __restrict__ VAL,
    const u16* __restrict__ AW1, const u16* __restrict__ X0,
    const u16* __restrict__ cb1, u16* __restrict__ CH1)
{
    __shared__ __align__(16) u16 smem[9216];
    int bid = blockIdx.x;
    if (bid < 960) gemm_body<0, 1, 1>(smem, bid, AVW, CATT, vb, VAL, 128, 256, 0, 0, nullptr);
    else           conv_body<128, 0>(smem, bid - 960, AW1, X0, cb1, CH1, 256);
}

// ===========================================================================
// fused prep: per-block inline dtype detect; then one of
//   [0,3718)     : weight canon/transpose (951808 elems)
//   [3718,4678)  : feature transpose -> CATT (LDS tile, coalesced both sides)
//   [4678,4774)  : feature transpose -> X0
// ===========================================================================
struct P21 { const void* p[21]; };
// p[]: 0 cw1,1 cb1,2 cw2,3 cb2,4 cw3,5 cb3,6 vw,7 vb,8 lvl,
//      9 sw0,10 sb0,11 aw0,12 ab0,13 ow0,14 ob0, 15 sw1,16 sb1,17 aw1,18 ab1,19 ow1,20 ob1

__global__ __launch_bounds__(256) void prep_fused(
    P21 a, const void* __restrict__ f00, const void* __restrict__ f01,
    const void* __restrict__ f10, const void* __restrict__ f11,
    int* __restrict__ FLAG,
    u16* AW1, u16* AW2, u16* AW3, u16* AVW,
    u16* APJ0, u16* APJ1, u16* AOP0, u16* AOP1,
    u16* BPJ0, u16* BPJ1, u16* SB,
    u16* CATT, u16* X0)
{
    __shared__ __align__(16) u16 Ts[128 * 66];        // transpose tile [128c][66]
    const int t = threadIdx.x;
    // inline dtype detect (all blocks, 1KB of f00 — L2-broadcast)
    unsigned int w = ((const unsigned int*)f00)[t];
    float pa = fabsf(bf2f((u16)(w & 0xFFFFu)));
    int cnt = __syncthreads_count(pa > 1e-6f && pa < 1e4f);
    const int f32 = (cnt < 128);
    const int bid = blockIdx.x;
    if (bid == 0 && t == 0) *FLAG = f32;

    if (bid < 3718) {
        int g = bid * 256 + t;
        if (g < 294912) { int m = g / 1152, rem = g % 1152, tap = rem >> 7, ci = rem & 127;
            AW1[g] = f2bf(ldv(a.p[0], (size_t)m * 1152 + ci * 9 + tap, f32)); return; }
        g -= 294912;
        if (g < 294912) { int m = g / 2304, rem = g % 2304, tap = rem >> 8, ci = rem & 255;
            AW2[g] = f2bf(ldv(a.p[2], (size_t)m * 2304 + ci * 9 + tap, f32)); return; }
        g -= 294912;
        if (g < 147456) { int m = g / 1152, rem = g % 1152, tap = rem >> 7, ci = rem & 127;
            AW3[g] = f2bf(ldv(a.p[4], (size_t)m * 1152 + ci * 9 + tap, f32)); return; }
        g -= 147456;
        if (g < 32768) { AVW[g] = f2bf(ldv(a.p[6], g, f32)); return; }
        g -= 32768;
        if (g < 24576) { int o = g >> 7, d = g & 127;
            APJ0[g] = f2bf(o < 128 ? ldv(a.p[9], d * 128 + o, f32)
                                   : ldv(a.p[11], d * 64 + (o - 128), f32)); return; }
        g -= 24576;
        if (g < 24576) { int o = g >> 7, d = g & 127;
            APJ1[g] = f2bf(o < 128 ? ldv(a.p[15], d * 128 + o, f32)
                                   : ldv(a.p[17], d * 64 + (o - 128), f32)); return; }
        g -= 24576;
        if (g < 65536) { int o = g >> 9, k = g & 511; AOP0[g] = f2bf(ldv(a.p[13], k * 128 + o, f32)); return; }
        g -= 65536;
        if (g < 65536) { int o = g >> 9, k = g & 511; AOP1[g] = f2bf(ldv(a.p[19], k * 128 + o, f32)); return; }
        g -= 65536;
        if (g < 192) { BPJ0[g] = f2bf(g < 128 ? ldv(a.p[10], g, f32) : ldv(a.p[12], g - 128, f32)); return; }
        g -= 192;
        if (g < 192) { BPJ1[g] = f2bf(g < 128 ? ldv(a.p[16], g, f32) : ldv(a.p[18], g - 128, f32)); return; }
        g -= 192;
        if (g < 1152) {
            const int off[8] = {0, 256, 384, 512, 640, 896, 1024, 1152};
            const int src[7] = {1, 3, 5, 7, 8, 14, 20};
            int s = 0;
            #pragma unroll
            for (int i = 1; i < 7; ++i) s += (g >= off[i]);
            SB[g] = f2bf(ldv(a.p[src[s]], g - off[s], f32));
        }
        return;
    }

    // -------- feature transposes via LDS tile --------
    // CATT region: 960 blocks = b(4) x lvl-tile(120: 96 lvl0 + 24 lvl1) x half(2)
    // X0 region:    96 blocks = b(4) x tile(24)
    const void* src; u16* dst;
    int b, hw0, HW, rowlen, coloff, lvl, addemb;
    if (bid < 4678) {
        int g = bid - 3718;
        int half = g & 1;  g >>= 1;                   // 480 = 4b x 120 tiles
        b = g / 120;  int tile = g % 120;
        lvl = (tile >= 96) ? 1 : 0;
        int tl = lvl ? tile - 96 : tile;
        hw0 = tl << 6;
        HW = lvl ? 1536 : 6144;
        src = (half == 0) ? (lvl ? f01 : f00) : (lvl ? f11 : f10);
        dst = CATT + (size_t)(b * 7680 + lvl * 6144 + hw0) * 256;
        rowlen = 256; coloff = half << 7; addemb = 1;
    } else {
        int g = bid - 4678;                           // 96 = 4b x 24 tiles
        b = g / 24;  hw0 = (g % 24) << 6;
        HW = 1536; src = f01;
        dst = X0 + (size_t)(b * 1536 + hw0) * 128;
        rowlen = 128; coloff = 0; lvl = 1; addemb = 0;
    }

    // stage-in: thread t -> c = t>>1 (0..127), hseg = (t&1)*32; 64B contiguous
    {
        int c = t >> 1, hseg = (t & 1) << 5;
        size_t base = (size_t)(b * 128 + c) * HW + hw0 + hseg;
        u16* dstl = &Ts[c * 66 + hseg];
        if (!f32) {
            const u16* s8 = (const u16*)src + base;
            *(uint4*)(dstl)      = *(const uint4*)(s8);
            *(uint4*)(dstl + 8)  = *(const uint4*)(s8 + 8);
            *(uint4*)(dstl + 16) = *(const uint4*)(s8 + 16);
            *(uint4*)(dstl + 24) = *(const uint4*)(s8 + 24);
        } else {
            const float* sf = (const float*)src + base;
            #pragma unroll
            for (int q = 0; q < 32; ++q) dstl[q] = f2bf(sf[q]);
        }
    }
    __syncthreads();
    // read-out: thread t -> tok = t&63, cseg = (t>>6)*32; column reads 2-way only
    {
        int tok = t & 63, cseg = (t >> 6) << 5;
        u16 outv[32];
        #pragma unroll
        for (int j = 0; j < 32; ++j) {
            float x = bf2f(Ts[(cseg + j) * 66 + tok]);
            if (addemb) x += ldv(a.p[8], lvl * 128 + cseg + j, f32);
            outv[j] = f2bf(x);
        }
        u16* drow = dst + (size_t)tok * rowlen + coloff + cseg;
        #pragma unroll
        for (int q = 0; q < 4; ++q)
            *(uint4*)(drow + q * 8) = *(const uint4*)(&outv[q * 8]);
    }
}

// ===========================================================================
// MSDeformAttn sampling (+softmax), vectorized gather, XCD-chunked swizzle
// ===========================================================================
__global__ void msda_sample(const float* __restrict__ PA, const u16* __restrict__ VAL,
                            u16* __restrict__ S)
{
    __shared__ int   SMI[4][64];
    __shared__ float SMW[4][64];
    __shared__ float LG[64];
    __shared__ float EW[64];
    int bid = blockIdx.x;                 // 6144 = 8 * 768
    int tok = ((bid & 7) * 768) + (bid >> 3);
    int t = threadIdx.x;                  // 128
    int b = tok / 1536, hw = tok % 1536;
    int hp = hw / 48, wp = hw % 48;

    if (t < 64) {
        int l = (t >> 3) & 1, p = t & 7, h = t >> 4;
        int orow = h * 32 + l * 16 + p * 2;
        float offx = PA[(size_t)orow * 6144 + tok];
        float offy = PA[(size_t)(orow + 1) * 6144 + tok];
        LG[t]      = PA[(size_t)(128 + h * 16 + l * 8 + p) * 6144 + tok];
        float Wl = l ? 48.f : 96.f, Hl = l ? 32.f : 64.f;
        int iWl = l ? 48 : 96, iHl = l ? 32 : 64;
        int base = l ? 6144 : 0;
        float locx = (wp + 0.5f) / 48.f + offx / Wl;
        float locy = (hp + 0.5f) / 32.f + offy / Hl;
        float x = locx * Wl - 0.5f;
        float y = locy * Hl - 0.5f;
        float xf = floorf(x), yf = floorf(y);
        float fx = x - xf, fy = y - yf;
        int ix = (int)xf, iy = (int)yf;
        int vrow = b * 7680 + base;
        float w00 = (1.f - fx) * (1.f - fy), w01 = fx * (1.f - fy);
        float w10 = (1.f - fx) * fy,         w11 = fx * fy;
        bool vx0 = (ix >= 0) & (ix < iWl),     vx1 = (ix + 1 >= 0) & (ix + 1 < iWl);
        bool vy0 = (iy >= 0) & (iy < iHl),     vy1 = (iy + 1 >= 0) & (iy + 1 < iHl);
        SMI[0][t] = (vx0 & vy0) ? vrow + iy * iWl + ix           : 0;
        SMI[1][t] = (vx1 & vy0) ? vrow + iy * iWl + ix + 1       : 0;
        SMI[2][t] = (vx0 & vy1) ? vrow + (iy + 1) * iWl + ix     : 0;
        SMI[3][t] = (vx1 & vy1) ? vrow + (iy + 1) * iWl + ix + 1 : 0;
        SMW[0][t] = (vx0 & vy0) ? w00 : 0.f;
        SMW[1][t] = (vx1 & vy0) ? w01 : 0.f;
        SMW[2][t] = (vx0 & vy1) ? w10 : 0.f;
        SMW[3][t] = (vx1 & vy1) ? w11 : 0.f;
    }
    __syncthreads();
    if (t < 64) {
        int h0 = t & ~15;
        float mx = -1e30f;
        for (int i = 0; i < 16; ++i) mx = fmaxf(mx, LG[h0 + i]);
        EW[t] = expf(LG[t] - mx);
    }
    __syncthreads();
    if (t < 64) {
        int h0 = t & ~15;
        float s = 0.f;
        for (int i = 0; i < 16; ++i) s += EW[h0 + i];
        float aw = EW[t] / s;
        SMW[0][t] *= aw; SMW[1][t] *= aw; SMW[2][t] *= aw; SMW[3][t] *= aw;
    }
    __syncthreads();

    const int h = t >> 5, sub = t & 31, dseg = sub & 15, half = sub >> 4;
    const u16* Vb = VAL + (size_t)dseg * 8;
    float acc[8] = {0.f, 0.f, 0.f, 0.f, 0.f, 0.f, 0.f, 0.f};
    #pragma unroll 8
    for (int r = 0; r < 32; ++r) {
        int pr = (half << 5) + r;
        int s = pr >> 2, c = pr & 3;
        float w  = SMW[c][(h << 4) + s];
        int  idx = SMI[c][(h << 4) + s];
        u16x8 v = *(const u16x8*)(Vb + (size_t)idx * 128);
        #pragma unroll
        for (int j = 0; j < 8; ++j) acc[j] += w * bf2f(v[j]);
    }
    #pragma unroll
    for (int j = 0; j < 8; ++j) acc[j] += __shfl_xor(acc[j], 16, 64);
    if (!half) {
        u16x8 o;
        #pragma unroll
        for (int j = 0; j < 8; ++j) o[j] = f2bf(acc[j]);
        *(u16x8*)(S + (size_t)tok * 512 + (h << 7) + (dseg << 3)) = o;
    }
}

// ---------------------------------------------------------------------------
extern "C" void kernel_launch(void* const* d_in, const int* in_sizes, int n_in,
                              void* d_out, int out_size, void* d_ws, size_t ws_size,
                              hipStream_t stream)
{
    (void)in_sizes; (void)n_in; (void)out_size; (void)ws_size;

    char* ws = (char*)d_ws;
    size_t off = 0;
    auto alloc = [&](size_t bytes) { size_t o = off; off += (bytes + 255) & ~(size_t)255; return o; };
    int*   FLAG = (int*)(ws + alloc(256));
    u16*   AW1  = (u16*)(ws + alloc(294912ull * 2));
    u16*   AW2  = (u16*)(ws + alloc(294912ull * 2));
    u16*   AW3  = (u16*)(ws + alloc(147456ull * 2));
    u16*   AVW  = (u16*)(ws + alloc(32768ull * 2));
    u16*   APJ0 = (u16*)(ws + alloc(24576ull * 2));
    u16*   APJ1 = (u16*)(ws + alloc(24576ull * 2));
    u16*   AOP0 = (u16*)(ws + alloc(65536ull * 2));
    u16*   AOP1 = (u16*)(ws + alloc(65536ull * 2));
    u16*   BPJ0 = (u16*)(ws + alloc(512));
    u16*   BPJ1 = (u16*)(ws + alloc(512));
    u16*   SB   = (u16*)(ws + alloc(1152ull * 2));
    u16*   VAL  = (u16*)(ws + alloc(30720ull * 128 * 2));
    u16*   X0   = (u16*)(ws + alloc(6144ull * 128 * 2));
    u16*   CH1  = (u16*)(ws + alloc(6144ull * 256 * 2));
    u16*   CH2  = (u16*)(ws + alloc(6144ull * 128 * 2));
    u16*   QT0  = (u16*)(ws + alloc(6144ull * 128 * 2));
    u16*   QT1  = (u16*)(ws + alloc(6144ull * 128 * 2));
    char*  R    = ws + alloc(30720ull * 256 * 2);          // union: CATT | PA+S
    u16*   CATT = (u16*)R;
    float* PA   = (float*)R;
    u16*   S    = (u16*)(R + 192ull * 6144 * 4);

    u16* cb1C = SB + 0;   u16* cb2C = SB + 256;  u16* cb3C = SB + 384;
    u16* vbC  = SB + 512;
    u16* ob0C = SB + 896; u16* ob1C = SB + 1024;

    P21 a;
    const int widx[21] = {4,5,6,7,8,9,10,11,12, 13,14,15,16,17,18, 19,20,21,22,23,24};
    for (int i = 0; i < 21; ++i) a.p[i] = d_in[widx[i]];

    // 1. fused prep: weights + CATT + X0 (+FLAG publish)
    prep_fused<<<4774, 256, 0, stream>>>(a, d_in[0], d_in[1], d_in[2], d_in[3], FLAG,
                                         AW1, AW2, AW3, AVW,
                                         APJ0, APJ1, AOP0, AOP1, BPJ0, BPJ1, SB,
                                         CATT, X0);

    // 2. value GEMM || conv1 (fat kernel, independent grids)
    val_conv1_k<<<960 + 384, 256, 0, stream>>>(AVW, CATT, vbC, VAL, AW1, X0, cb1C, CH1);

    // 3. conv2, conv3(+pos)
    conv_gemm<256, 0><<<2 * 96, 256, 0, stream>>>(AW2, CH1, cb2C, CH2, 128);
    conv_gemm<128, 1><<<2 * 96, 256, 0, stream>>>(AW3, CH2, cb3C, QT0, 128);

    // 4. attention block 0
    gemm_kn<0, 0, 0><<<3 * 96, 256, 0, stream>>>(APJ0, QT0, BPJ0, PA, 192, 128, 6144, 0, FLAG);
    msda_sample<<<6144, 128, 0, stream>>>(PA, VAL, S);
    gemm_kn<0, 1, 1><<<2 * 96, 256, 0, stream>>>(AOP0, S, ob0C, QT1, 128, 512, 0, 0, FLAG);

    // 5. attention block 1 (final GEMM writes NCHW d_out directly)
    gemm_kn<0, 0, 0><<<3 * 96, 256, 0, stream>>>(APJ1, QT1, BPJ1, PA, 192, 128, 6144, 0, FLAG);
    msda_sample<<<6144, 128, 0, stream>>>(PA, VAL, S);
    gemm_kn<0, 2, 1><<<2 * 96, 256, 0, stream>>>(AOP1, S, ob1C, d_out, 128, 512, 0, 0, FLAG);
}

// Round 7
// 143.585 us; speedup vs baseline: 4.6365x; 1.0711x over previous
//
#include <hip/hip_runtime.h>
#include <hip/hip_bf16.h>

typedef unsigned short u16;
typedef u16   u16x8 __attribute__((ext_vector_type(8)));
typedef short s16x8 __attribute__((ext_vector_type(8)));
typedef float f32x4 __attribute__((ext_vector_type(4)));

__device__ __forceinline__ float bf2f(u16 u) {
    union { unsigned int i; float f; } v; v.i = ((unsigned int)u) << 16; return v.f;
}
__device__ __forceinline__ u16 f2bf(float f) {
    unsigned int x = __float_as_uint(f);
    return (u16)((x + 0x7fffu + ((x >> 16) & 1u)) >> 16);   // RNE
}
__device__ __forceinline__ float ldv(const void* p, size_t i, int f32) {
    return f32 ? ((const float*)p)[i] : bf2f(((const u16*)p)[i]);
}

// ===========================================================================
// GEMM core, BK=64, tile 64 x BN (BN = 64 or 32). 4 waves.
// OUTM=0: C[m][nbase+n] (ldc). OUTM=1: C^T[nbase+n][m] bounce. OUTM=2: NCHW out.
// BN=32 doubles grid for small-N GEMMs -> better CU fill (grid was < 256).
// ===========================================================================
template<int ACT, int OUTM, int OUT_BF16, int BN>
__device__ __forceinline__ void gemm_body(
    u16* __restrict__ smem, int bid,
    const u16* __restrict__ A, const u16* __restrict__ Bt,
    const u16* __restrict__ bias, void* __restrict__ Cv,
    int M, int K, int ldc, int nbase, const int* __restrict__ flag)
{
    constexpr int NF = BN >> 4;
    u16 (*As)[72] = (u16(*)[72])smem;                 // [64][72]
    u16 (*Bs)[72] = (u16(*)[72])(smem + 4608);        // [BN][72]

    const int t    = threadIdx.x;
    const int wv   = t >> 6, lane = t & 63;
    const int fr   = lane & 15, fg = lane >> 4;
    const int tiles_m = M >> 6;
    const int bm = bid % tiles_m, bn = bid / tiles_m;
    const int m0 = bm << 6, n0 = bn * BN;

    f32x4 acc[NF] = {};
    const int srow = t >> 2;
    const int scol = (t & 3) << 4;                    // A: 4 thr/row x 16 elems
    const int brow = (BN == 64) ? srow : (t >> 3);    // B: BN=32 -> 8 thr/row x 8
    const int bcol = (BN == 64) ? scol : ((t & 7) << 3);
    const u16* Ap = A  + (size_t)(m0 + srow) * K + scol;
    const u16* Bp = Bt + (size_t)(n0 + brow) * K + bcol;

    const int ns = K >> 6;
    uint4 av0 = *(const uint4*)Ap, av1 = *(const uint4*)(Ap + 8);
    uint4 bv0 = *(const uint4*)Bp, bv1 = {0,0,0,0};
    if constexpr (BN == 64) bv1 = *(const uint4*)(Bp + 8);
    for (int s = 0; s < ns; ++s) {
        __syncthreads();
        *(uint4*)&As[srow][scol]     = av0;  *(uint4*)&As[srow][scol + 8] = av1;
        *(uint4*)&Bs[brow][bcol]     = bv0;
        if constexpr (BN == 64) *(uint4*)&Bs[brow][bcol + 8] = bv1;
        __syncthreads();
        if (s + 1 < ns) {
            const u16* An = Ap + ((s + 1) << 6);
            const u16* Bn = Bp + ((s + 1) << 6);
            av0 = *(const uint4*)An;  av1 = *(const uint4*)(An + 8);
            bv0 = *(const uint4*)Bn;
            if constexpr (BN == 64) bv1 = *(const uint4*)(Bn + 8);
        }
        union U { uint4 q; s16x8 v; };
        #pragma unroll
        for (int kk = 0; kk < 2; ++kk) {
            U af; af.q = *(const uint4*)&As[(wv << 4) + fr][(kk << 5) + (fg << 3)];
            U bf[NF];
            #pragma unroll
            for (int j = 0; j < NF; ++j)
                bf[j].q = *(const uint4*)&Bs[(j << 4) + fr][(kk << 5) + (fg << 3)];
            #pragma unroll
            for (int j = 0; j < NF; ++j)
                acc[j] = __builtin_amdgcn_mfma_f32_16x16x32_bf16(af.v, bf[j].v, acc[j], 0, 0, 0);
        }
    }

    float vv[NF][4];
    #pragma unroll
    for (int r = 0; r < 4; ++r) {
        float bvv = bf2f(bias[m0 + (wv << 4) + (fg << 2) + r]);
        #pragma unroll
        for (int j = 0; j < NF; ++j) {
            float v = acc[j][r] + bvv;
            if (ACT) v = (v >= 0.f) ? v : 0.1f * v;
            vv[j][r] = v;
        }
    }

    if constexpr (OUTM == 0) {
        #pragma unroll
        for (int j = 0; j < NF; ++j)
            #pragma unroll
            for (int r = 0; r < 4; ++r) {
                size_t idx = (size_t)(m0 + (wv << 4) + (fg << 2) + r) * ldc
                           + (nbase + n0 + (j << 4) + fr);
                if (OUT_BF16) ((u16*)Cv)[idx] = f2bf(vv[j][r]);
                else          ((float*)Cv)[idx] = vv[j][r];
            }
    } else if constexpr (OUTM == 1) {
        __syncthreads();
        u16* bb = smem;                                 // [BN n][72 m]
        #pragma unroll
        for (int j = 0; j < NF; ++j)
            #pragma unroll
            for (int r = 0; r < 4; ++r)
                bb[((j << 4) + fr) * 72 + (wv << 4) + (fg << 2) + r] = f2bf(vv[j][r]);
        __syncthreads();
        if constexpr (BN == 64) {
            int row = t >> 2, seg = (t & 3) << 4;
            const uint4* src = (const uint4*)&bb[row * 72 + seg];
            uint4* dst = (uint4*)((u16*)Cv + (size_t)(nbase + n0 + row) * M + m0 + seg);
            dst[0] = src[0];
            dst[1] = src[1];
        } else {
            int row = t >> 3, seg = (t & 7) << 3;
            const uint4* src = (const uint4*)&bb[row * 72 + seg];
            uint4* dst = (uint4*)((u16*)Cv + (size_t)(nbase + n0 + row) * M + m0 + seg);
            dst[0] = src[0];
        }
    } else {
        // NCHW final: out[b][m][hw]; n-tile never crosses a batch (1536%BN==0)
        __syncthreads();
        constexpr int LDB = BN + 8;
        u16* bb = smem;                                 // [64 m][LDB n]
        #pragma unroll
        for (int j = 0; j < NF; ++j)
            #pragma unroll
            for (int r = 0; r < 4; ++r)
                bb[((wv << 4) + (fg << 2) + r) * LDB + (j << 4) + fr] = f2bf(vv[j][r]);
        __syncthreads();
        int f32o = *flag;
        constexpr int EPT = BN / 4;                     // 16 or 8 per thread
        int mrow = t >> 2, seg = (t & 3) * EPT;
        int b = n0 / 1536, hw0 = (n0 % 1536) + seg;
        size_t base = (size_t)(b * 128 + m0 + mrow) * 1536 + hw0;
        if (!f32o) {
            #pragma unroll
            for (int q = 0; q < EPT / 8; ++q)
                *(uint4*)((u16*)Cv + base + q * 8) = *(const uint4*)&bb[mrow * LDB + seg + q * 8];
        } else {
            float* dst = (float*)Cv + base;
            #pragma unroll
            for (int j = 0; j < EPT; ++j) dst[j] = bf2f(bb[mrow * LDB + seg + j]);
        }
    }
}

// ===========================================================================
// Implicit-GEMM 3x3 conv (pad 1), BK=64, tile 64 x BN.
// POS=1 fuses the sine positional encoding into the epilogue.
// ===========================================================================
template<int CIN, int POS, int BN>
__device__ __forceinline__ void conv_body(
    u16* __restrict__ smem, int bid,
    const u16* __restrict__ A, const u16* __restrict__ X,
    const u16* __restrict__ bias, u16* __restrict__ Cv, int M)
{
    constexpr int NF = BN >> 4;
    u16 (*As)[72] = (u16(*)[72])smem;
    u16 (*Bs)[72] = (u16(*)[72])(smem + 4608);

    constexpr int NK2 = CIN / 64;       // 2 or 4
    constexpr int TOT = 9 * NK2;

    const int t    = threadIdx.x;
    const int wv   = t >> 6, lane = t & 63;
    const int fr   = lane & 15, fg = lane >> 4;
    const int tiles_m = M >> 6;
    const int bm = bid % tiles_m, bn = bid / tiles_m;
    const int m0 = bm << 6, n0 = bn * BN;

    const int srow = t >> 2;
    const int scol = (t & 3) << 4;
    const int brow = (BN == 64) ? srow : (t >> 3);
    const int bcol = (BN == 64) ? scol : ((t & 7) << 3);
    const int n  = n0 + brow;
    const int hw = n % 1536;
    const int hp = hw / 48, wp = hw % 48;
    const u16* Ar = A + (size_t)(m0 + srow) * (9 * CIN) + scol;

    f32x4 acc[NF] = {};

    auto ld = [&](int s, uint4& a0, uint4& a1, uint4& b0, uint4& b1) {
        int tap = s / NK2, k0 = (s % NK2) << 6;
        int dy = tap / 3 - 1, dx = tap % 3 - 1;
        bool vr = ((unsigned)(hp + dy) < 32u) && ((unsigned)(wp + dx) < 48u);
        const u16* Ap = Ar + tap * CIN + k0;
        a0 = *(const uint4*)Ap;  a1 = *(const uint4*)(Ap + 8);
        if (vr) {
            const u16* Bp = X + (size_t)(n + dy * 48 + dx) * CIN + bcol + k0;
            b0 = *(const uint4*)Bp;
            if constexpr (BN == 64) b1 = *(const uint4*)(Bp + 8);
        } else {
            b0 = uint4{0,0,0,0};  b1 = uint4{0,0,0,0};
        }
    };

    uint4 av0, av1, bv0, bv1;
    ld(0, av0, av1, bv0, bv1);
    for (int s = 0; s < TOT; ++s) {
        __syncthreads();
        *(uint4*)&As[srow][scol]     = av0;  *(uint4*)&As[srow][scol + 8] = av1;
        *(uint4*)&Bs[brow][bcol]     = bv0;
        if constexpr (BN == 64) *(uint4*)&Bs[brow][bcol + 8] = bv1;
        __syncthreads();
        if (s + 1 < TOT) ld(s + 1, av0, av1, bv0, bv1);
        union U { uint4 q; s16x8 v; };
        #pragma unroll
        for (int kk = 0; kk < 2; ++kk) {
            U af; af.q = *(const uint4*)&As[(wv << 4) + fr][(kk << 5) + (fg << 3)];
            U bf[NF];
            #pragma unroll
            for (int j = 0; j < NF; ++j)
                bf[j].q = *(const uint4*)&Bs[(j << 4) + fr][(kk << 5) + (fg << 3)];
            #pragma unroll
            for (int j = 0; j < NF; ++j)
                acc[j] = __builtin_amdgcn_mfma_f32_16x16x32_bf16(af.v, bf[j].v, acc[j], 0, 0, 0);
        }
    }

    float vv[NF][4];
    #pragma unroll
    for (int r = 0; r < 4; ++r) {
        float bvv = bf2f(bias[m0 + (wv << 4) + (fg << 2) + r]);
        #pragma unroll
        for (int j = 0; j < NF; ++j) {
            float v = acc[j][r] + bvv;
            vv[j][r] = (v >= 0.f) ? v : 0.1f * v;
        }
    }

    if (POS) {
        const float TWO_PI = 6.283185307179586f;
        #pragma unroll
        for (int j = 0; j < NF; ++j) {
            int ntok = n0 + (j << 4) + fr;
            int hw2 = ntok % 1536;
            int hp2 = hw2 / 48, wp2 = hw2 % 48;
            float yv = (float)(hp2 + 1) * (TWO_PI / (32.f + 1e-6f));
            float xv = (float)(wp2 + 1) * (TWO_PI / (48.f + 1e-6f));
            #pragma unroll
            for (int r = 0; r < 4; ++r) {
                int d = m0 + (wv << 4) + (fg << 2) + r;
                int mm = (d & 63) >> 1;
                float dim = exp2f((float)mm * (13.287712379549449f / 32.f));
                float val = ((d < 64) ? yv : xv) / dim;
                vv[j][r] += (d & 1) ? cosf(val) : sinf(val);
            }
        }
    }

    __syncthreads();
    u16* bb = smem;                                     // [BN n][72 m]
    #pragma unroll
    for (int j = 0; j < NF; ++j)
        #pragma unroll
        for (int r = 0; r < 4; ++r)
            bb[((j << 4) + fr) * 72 + (wv << 4) + (fg << 2) + r] = f2bf(vv[j][r]);
    __syncthreads();
    if constexpr (BN == 64) {
        int row = t >> 2, seg = (t & 3) << 4;
        const uint4* src = (const uint4*)&bb[row * 72 + seg];
        uint4* dst = (uint4*)(Cv + (size_t)(n0 + row) * M + m0 + seg);
        dst[0] = src[0];
        dst[1] = src[1];
    } else {
        int row = t >> 3, seg = (t & 7) << 3;
        const uint4* src = (const uint4*)&bb[row * 72 + seg];
        uint4* dst = (uint4*)(Cv + (size_t)(n0 + row) * M + m0 + seg);
        dst[0] = src[0];
    }
}

// ---------------------------------------------------------------------------
template<int ACT, int OUTM, int OUT_BF16, int BN>
__global__ __launch_bounds__(256) void gemm_kn(
    const u16* __restrict__ A, const u16* __restrict__ Bt,
    const u16* __restrict__ bias, void* __restrict__ Cv,
    int M, int K, int ldc, int nbase, const int* __restrict__ flag)
{
    __shared__ __align__(16) u16 smem[9216];
    gemm_body<ACT, OUTM, OUT_BF16, BN>(smem, blockIdx.x, A, Bt, bias, Cv, M, K, ldc, nbase, flag);
}

template<int CIN, int POS, int BN>
__global__ __launch_bounds__(256) void conv_gemm(
    const u16* __restrict__ A, const u16* __restrict__ X,
    const u16* __restrict__ bias, u16* __restrict__ Cv, int M)
{
    __shared__ __align__(16) u16 smem[9216];
    conv_body<CIN, POS, BN>(smem, blockIdx.x, A, X, bias, Cv, M);
}

// fat kernel: value GEMM (960 blocks) || conv1 (384 blocks) — independent work
__global__ __launch_bounds__(256) void val_conv1_k(
    const u16* __restrict__ AVW, const u16* __restrict__ CATT,
    const u16* __restrict__ vb, u16* __restrict__ VAL,
    const u16* __restrict__ AW1, const u16* __restrict__ X0,
    const u16* __restrict__ cb1, u16* __restrict__ CH1)
{
    __shared__ __align__(16) u16 smem[9216];
    int bid = blockIdx.x;
    if (bid < 960) gemm_body<0, 1, 1, 64>(smem, bid, AVW, CATT, vb, VAL, 128, 256, 0, 0, nullptr);
    else           conv_body<128, 0, 64>(smem, bid - 960, AW1, X0, cb1, CH1, 256);
}

// ===========================================================================
// fused prep: per-block inline dtype detect; then one of
//   [0,3718)     : weight canon/transpose (951808 elems)
//   [3718,4678)  : feature transpose -> CATT (LDS tile, coalesced both sides)
//   [4678,4774)  : feature transpose -> X0
// ===========================================================================
struct P21 { const void* p[21]; };
// p[]: 0 cw1,1 cb1,2 cw2,3 cb2,4 cw3,5 cb3,6 vw,7 vb,8 lvl,
//      9 sw0,10 sb0,11 aw0,12 ab0,13 ow0,14 ob0, 15 sw1,16 sb1,17 aw1,18 ab1,19 ow1,20 ob1

__global__ __launch_bounds__(256) void prep_fused(
    P21 a, const void* __restrict__ f00, const void* __restrict__ f01,
    const void* __restrict__ f10, const void* __restrict__ f11,
    int* __restrict__ FLAG,
    u16* AW1, u16* AW2, u16* AW3, u16* AVW,
    u16* APJ0, u16* APJ1, u16* AOP0, u16* AOP1,
    u16* BPJ0, u16* BPJ1, u16* SB,
    u16* CATT, u16* X0)
{
    __shared__ __align__(16) u16 Ts[128 * 66];        // transpose tile [128c][66]
    const int t = threadIdx.x;
    // inline dtype detect (all blocks, 1KB of f00 — L2-broadcast)
    unsigned int w = ((const unsigned int*)f00)[t];
    float pa = fabsf(bf2f((u16)(w & 0xFFFFu)));
    int cnt = __syncthreads_count(pa > 1e-6f && pa < 1e4f);
    const int f32 = (cnt < 128);
    const int bid = blockIdx.x;
    if (bid == 0 && t == 0) *FLAG = f32;

    if (bid < 3718) {
        int g = bid * 256 + t;
        if (g < 294912) { int m = g / 1152, rem = g % 1152, tap = rem >> 7, ci = rem & 127;
            AW1[g] = f2bf(ldv(a.p[0], (size_t)m * 1152 + ci * 9 + tap, f32)); return; }
        g -= 294912;
        if (g < 294912) { int m = g / 2304, rem = g % 2304, tap = rem >> 8, ci = rem & 255;
            AW2[g] = f2bf(ldv(a.p[2], (size_t)m * 2304 + ci * 9 + tap, f32)); return; }
        g -= 294912;
        if (g < 147456) { int m = g / 1152, rem = g % 1152, tap = rem >> 7, ci = rem & 127;
            AW3[g] = f2bf(ldv(a.p[4], (size_t)m * 1152 + ci * 9 + tap, f32)); return; }
        g -= 147456;
        if (g < 32768) { AVW[g] = f2bf(ldv(a.p[6], g, f32)); return; }
        g -= 32768;
        if (g < 24576) { int o = g >> 7, d = g & 127;
            APJ0[g] = f2bf(o < 128 ? ldv(a.p[9], d * 128 + o, f32)
                                   : ldv(a.p[11], d * 64 + (o - 128), f32)); return; }
        g -= 24576;
        if (g < 24576) { int o = g >> 7, d = g & 127;
            APJ1[g] = f2bf(o < 128 ? ldv(a.p[15], d * 128 + o, f32)
                                   : ldv(a.p[17], d * 64 + (o - 128), f32)); return; }
        g -= 24576;
        if (g < 65536) { int o = g >> 9, k = g & 511; AOP0[g] = f2bf(ldv(a.p[13], k * 128 + o, f32)); return; }
        g -= 65536;
        if (g < 65536) { int o = g >> 9, k = g & 511; AOP1[g] = f2bf(ldv(a.p[19], k * 128 + o, f32)); return; }
        g -= 65536;
        if (g < 192) { BPJ0[g] = f2bf(g < 128 ? ldv(a.p[10], g, f32) : ldv(a.p[12], g - 128, f32)); return; }
        g -= 192;
        if (g < 192) { BPJ1[g] = f2bf(g < 128 ? ldv(a.p[16], g, f32) : ldv(a.p[18], g - 128, f32)); return; }
        g -= 192;
        if (g < 1152) {
            const int off[8] = {0, 256, 384, 512, 640, 896, 1024, 1152};
            const int src[7] = {1, 3, 5, 7, 8, 14, 20};
            int s = 0;
            #pragma unroll
            for (int i = 1; i < 7; ++i) s += (g >= off[i]);
            SB[g] = f2bf(ldv(a.p[src[s]], g - off[s], f32));
        }
        return;
    }

    // -------- feature transposes via LDS tile --------
    const void* src; u16* dst;
    int b, hw0, HW, rowlen, coloff, lvl, addemb;
    if (bid < 4678) {
        int g = bid - 3718;
        int half = g & 1;  g >>= 1;                   // 480 = 4b x 120 tiles
        b = g / 120;  int tile = g % 120;
        lvl = (tile >= 96) ? 1 : 0;
        int tl = lvl ? tile - 96 : tile;
        hw0 = tl << 6;
        HW = lvl ? 1536 : 6144;
        src = (half == 0) ? (lvl ? f01 : f00) : (lvl ? f11 : f10);
        dst = CATT + (size_t)(b * 7680 + lvl * 6144 + hw0) * 256;
        rowlen = 256; coloff = half << 7; addemb = 1;
    } else {
        int g = bid - 4678;                           // 96 = 4b x 24 tiles
        b = g / 24;  hw0 = (g % 24) << 6;
        HW = 1536; src = f01;
        dst = X0 + (size_t)(b * 1536 + hw0) * 128;
        rowlen = 128; coloff = 0; lvl = 1; addemb = 0;
    }

    {
        int c = t >> 1, hseg = (t & 1) << 5;
        size_t base = (size_t)(b * 128 + c) * HW + hw0 + hseg;
        u16* dstl = &Ts[c * 66 + hseg];
        if (!f32) {
            const u16* s8 = (const u16*)src + base;
            *(uint4*)(dstl)      = *(const uint4*)(s8);
            *(uint4*)(dstl + 8)  = *(const uint4*)(s8 + 8);
            *(uint4*)(dstl + 16) = *(const uint4*)(s8 + 16);
            *(uint4*)(dstl + 24) = *(const uint4*)(s8 + 24);
        } else {
            const float* sf = (const float*)src + base;
            #pragma unroll
            for (int q = 0; q < 32; ++q) dstl[q] = f2bf(sf[q]);
        }
    }
    __syncthreads();
    {
        int tok = t & 63, cseg = (t >> 6) << 5;
        u16 outv[32];
        #pragma unroll
        for (int j = 0; j < 32; ++j) {
            float x = bf2f(Ts[(cseg + j) * 66 + tok]);
            if (addemb) x += ldv(a.p[8], lvl * 128 + cseg + j, f32);
            outv[j] = f2bf(x);
        }
        u16* drow = dst + (size_t)tok * rowlen + coloff + cseg;
        #pragma unroll
        for (int q = 0; q < 4; ++q)
            *(uint4*)(drow + q * 8) = *(const uint4*)(&outv[q * 8]);
    }
}

// ===========================================================================
// MSDeformAttn sampling (+softmax), batched gather (16 loads in flight/thread)
// ===========================================================================
__global__ void msda_sample(const float* __restrict__ PA, const u16* __restrict__ VAL,
                            u16* __restrict__ S)
{
    __shared__ int   SMI[4][64];
    __shared__ float SMW[4][64];
    __shared__ float LG[64];
    __shared__ float EW[64];
    int bid = blockIdx.x;                 // 6144 = 8 * 768
    int tok = ((bid & 7) * 768) + (bid >> 3);
    int t = threadIdx.x;                  // 128
    int b = tok / 1536, hw = tok % 1536;
    int hp = hw / 48, wp = hw % 48;

    if (t < 64) {
        int l = (t >> 3) & 1, p = t & 7, h = t >> 4;
        int orow = h * 32 + l * 16 + p * 2;
        float offx = PA[(size_t)orow * 6144 + tok];
        float offy = PA[(size_t)(orow + 1) * 6144 + tok];
        LG[t]      = PA[(size_t)(128 + h * 16 + l * 8 + p) * 6144 + tok];
        float Wl = l ? 48.f : 96.f, Hl = l ? 32.f : 64.f;
        int iWl = l ? 48 : 96, iHl = l ? 32 : 64;
        int base = l ? 6144 : 0;
        float locx = (wp + 0.5f) / 48.f + offx / Wl;
        float locy = (hp + 0.5f) / 32.f + offy / Hl;
        float x = locx * Wl - 0.5f;
        float y = locy * Hl - 0.5f;
        float xf = floorf(x), yf = floorf(y);
        float fx = x - xf, fy = y - yf;
        int ix = (int)xf, iy = (int)yf;
        int vrow = b * 7680 + base;
        float w00 = (1.f - fx) * (1.f - fy), w01 = fx * (1.f - fy);
        float w10 = (1.f - fx) * fy,         w11 = fx * fy;
        bool vx0 = (ix >= 0) & (ix < iWl),     vx1 = (ix + 1 >= 0) & (ix + 1 < iWl);
        bool vy0 = (iy >= 0) & (iy < iHl),     vy1 = (iy + 1 >= 0) & (iy + 1 < iHl);
        SMI[0][t] = (vx0 & vy0) ? vrow + iy * iWl + ix           : 0;
        SMI[1][t] = (vx1 & vy0) ? vrow + iy * iWl + ix + 1       : 0;
        SMI[2][t] = (vx0 & vy1) ? vrow + (iy + 1) * iWl + ix     : 0;
        SMI[3][t] = (vx1 & vy1) ? vrow + (iy + 1) * iWl + ix + 1 : 0;
        SMW[0][t] = (vx0 & vy0) ? w00 : 0.f;
        SMW[1][t] = (vx1 & vy0) ? w01 : 0.f;
        SMW[2][t] = (vx0 & vy1) ? w10 : 0.f;
        SMW[3][t] = (vx1 & vy1) ? w11 : 0.f;
    }
    __syncthreads();
    if (t < 64) {
        int h0 = t & ~15;
        float mx = -1e30f;
        for (int i = 0; i < 16; ++i) mx = fmaxf(mx, LG[h0 + i]);
        EW[t] = expf(LG[t] - mx);
    }
    __syncthreads();
    if (t < 64) {
        int h0 = t & ~15;
        float s = 0.f;
        for (int i = 0; i < 16; ++i) s += EW[h0 + i];
        float aw = EW[t] / s;
        SMW[0][t] *= aw; SMW[1][t] *= aw; SMW[2][t] *= aw; SMW[3][t] *= aw;
    }
    __syncthreads();

    const int h = t >> 5, sub = t & 31, dseg = sub & 15, half = sub >> 4;
    const u16* Vb = VAL + (size_t)dseg * 8;
    float acc[8] = {0.f, 0.f, 0.f, 0.f, 0.f, 0.f, 0.f, 0.f};
    #pragma unroll
    for (int rr = 0; rr < 32; rr += 16) {
        u16x8 vreg[16];
        float wreg[16];
        #pragma unroll
        for (int q = 0; q < 16; ++q) {
            int pr = (half << 5) + rr + q;
            int s = pr >> 2, c = pr & 3;
            wreg[q] = SMW[c][(h << 4) + s];
            vreg[q] = *(const u16x8*)(Vb + (size_t)SMI[c][(h << 4) + s] * 128);
        }
        #pragma unroll
        for (int q = 0; q < 16; ++q)
            #pragma unroll
            for (int j = 0; j < 8; ++j) acc[j] += wreg[q] * bf2f(vreg[q][j]);
    }
    #pragma unroll
    for (int j = 0; j < 8; ++j) acc[j] += __shfl_xor(acc[j], 16, 64);
    if (!half) {
        u16x8 o;
        #pragma unroll
        for (int j = 0; j < 8; ++j) o[j] = f2bf(acc[j]);
        *(u16x8*)(S + (size_t)tok * 512 + (h << 7) + (dseg << 3)) = o;
    }
}

// ---------------------------------------------------------------------------
extern "C" void kernel_launch(void* const* d_in, const int* in_sizes, int n_in,
                              void* d_out, int out_size, void* d_ws, size_t ws_size,
                              hipStream_t stream)
{
    (void)in_sizes; (void)n_in; (void)out_size; (void)ws_size;

    char* ws = (char*)d_ws;
    size_t off = 0;
    auto alloc = [&](size_t bytes) { size_t o = off; off += (bytes + 255) & ~(size_t)255; return o; };
    int*   FLAG = (int*)(ws + alloc(256));
    u16*   AW1  = (u16*)(ws + alloc(294912ull * 2));
    u16*   AW2  = (u16*)(ws + alloc(294912ull * 2));
    u16*   AW3  = (u16*)(ws + alloc(147456ull * 2));
    u16*   AVW  = (u16*)(ws + alloc(32768ull * 2));
    u16*   APJ0 = (u16*)(ws + alloc(24576ull * 2));
    u16*   APJ1 = (u16*)(ws + alloc(24576ull * 2));
    u16*   AOP0 = (u16*)(ws + alloc(65536ull * 2));
    u16*   AOP1 = (u16*)(ws + alloc(65536ull * 2));
    u16*   BPJ0 = (u16*)(ws + alloc(512));
    u16*   BPJ1 = (u16*)(ws + alloc(512));
    u16*   SB   = (u16*)(ws + alloc(1152ull * 2));
    u16*   VAL  = (u16*)(ws + alloc(30720ull * 128 * 2));
    u16*   X0   = (u16*)(ws + alloc(6144ull * 128 * 2));
    u16*   CH1  = (u16*)(ws + alloc(6144ull * 256 * 2));
    u16*   CH2  = (u16*)(ws + alloc(6144ull * 128 * 2));
    u16*   QT0  = (u16*)(ws + alloc(6144ull * 128 * 2));
    u16*   QT1  = (u16*)(ws + alloc(6144ull * 128 * 2));
    char*  R    = ws + alloc(30720ull * 256 * 2);          // union: CATT | PA+S
    u16*   CATT = (u16*)R;
    float* PA   = (float*)R;
    u16*   S    = (u16*)(R + 192ull * 6144 * 4);

    u16* cb1C = SB + 0;   u16* cb2C = SB + 256;  u16* cb3C = SB + 384;
    u16* vbC  = SB + 512;
    u16* ob0C = SB + 896; u16* ob1C = SB + 1024;

    P21 a;
    const int widx[21] = {4,5,6,7,8,9,10,11,12, 13,14,15,16,17,18, 19,20,21,22,23,24};
    for (int i = 0; i < 21; ++i) a.p[i] = d_in[widx[i]];

    // 1. fused prep: weights + CATT + X0 (+FLAG publish)
    prep_fused<<<4774, 256, 0, stream>>>(a, d_in[0], d_in[1], d_in[2], d_in[3], FLAG,
                                         AW1, AW2, AW3, AVW,
                                         APJ0, APJ1, AOP0, AOP1, BPJ0, BPJ1, SB,
                                         CATT, X0);

    // 2. value GEMM || conv1 (fat kernel, independent grids)
    val_conv1_k<<<960 + 384, 256, 0, stream>>>(AVW, CATT, vbC, VAL, AW1, X0, cb1C, CH1);

    // 3. conv2, conv3(+pos)  — BN=32: 384 blocks each
    conv_gemm<256, 0, 32><<<2 * 192, 256, 0, stream>>>(AW2, CH1, cb2C, CH2, 128);
    conv_gemm<128, 1, 32><<<2 * 192, 256, 0, stream>>>(AW3, CH2, cb3C, QT0, 128);

    // 4. attention block 0  — proj 576 blocks, out 384 blocks
    gemm_kn<0, 0, 0, 32><<<3 * 192, 256, 0, stream>>>(APJ0, QT0, BPJ0, PA, 192, 128, 6144, 0, FLAG);
    msda_sample<<<6144, 128, 0, stream>>>(PA, VAL, S);
    gemm_kn<0, 1, 1, 32><<<2 * 192, 256, 0, stream>>>(AOP0, S, ob0C, QT1, 128, 512, 0, 0, FLAG);

    // 5. attention block 1 (final GEMM writes NCHW d_out directly)
    gemm_kn<0, 0, 0, 32><<<3 * 192, 256, 0, stream>>>(APJ1, QT1, BPJ1, PA, 192, 128, 6144, 0, FLAG);
    msda_sample<<<6144, 128, 0, stream>>>(PA, VAL, S);
    gemm_kn<0, 2, 1, 32><<<2 * 192, 256, 0, stream>>>(AOP1, S, ob1C, d_out, 128, 512, 0, 0, FLAG);
}